// Round 13
// baseline (4127.998 us; speedup 1.0000x reference)
//
#include <hip/hip_runtime.h>

#define T_TOK 4096
#define SEQ   2048
#define HID   1024
#define NH    16
#define HD    64
#define INTER 4096
#define NLAYER 8
#define VOCAB 32000

typedef short short8 __attribute__((ext_vector_type(8)));
typedef float f32x4  __attribute__((ext_vector_type(4)));

__device__ __forceinline__ unsigned short f2bf(float f){
  unsigned int u = __builtin_bit_cast(unsigned int, f);
  u += 0x7fffu + ((u >> 16) & 1u);
  return (unsigned short)(u >> 16);
}
__device__ __forceinline__ float bf2f(unsigned short b){
  unsigned int u = ((unsigned int)b) << 16;
  return __builtin_bit_cast(float, u);
}

#define GLOAD_LDS16(gsrc, ldst) \
  __builtin_amdgcn_global_load_lds((const __attribute__((address_space(1))) void*)(gsrc), \
                                   (__attribute__((address_space(3))) void*)(ldst), 16, 0, 0)

// ---------------- embedding gather ----------------
__global__ __launch_bounds__(256) void embed_kernel(const int* __restrict__ ids,
                                                    const float* __restrict__ W,
                                                    float* __restrict__ h){
  int i = blockIdx.x * 256 + threadIdx.x;   // float4 index over [T][256]
  int t = i >> 8, c = i & 255;
  ((float4*)h)[i] = ((const float4*)(W + (size_t)ids[t] * HID))[c];
}

// ---------------- rope tables ----------------
__global__ __launch_bounds__(256) void rope_tab_kernel(float* __restrict__ cosT,
                                                       float* __restrict__ sinT){
  int i = blockIdx.x * 256 + threadIdx.x;   // s*32 + f
  int s = i >> 5, f = i & 31;
  float inv = expf(-((2.0f * (float)f) / 64.0f) * logf(100000.0f));
  float ang = (float)s * inv;
  cosT[i] = cosf(ang);
  sinT[i] = sinf(ang);
}

// ---------------- rmsnorm (fp32 in -> bf16 out, optional fp32 normed copy) ----------------
__global__ __launch_bounds__(256) void rmsnorm_kernel(const float* __restrict__ h,
                                                      const float* __restrict__ w,
                                                      unsigned short* __restrict__ out,
                                                      float* hcopy){
  int t = blockIdx.x, tid = threadIdx.x;
  float4 v = ((const float4*)(h + (size_t)t * HID))[tid];
  float ss = v.x*v.x + v.y*v.y + v.z*v.z + v.w*v.w;
  #pragma unroll
  for (int m = 1; m < 64; m <<= 1) ss += __shfl_xor(ss, m);
  __shared__ float red[4];
  if ((tid & 63) == 0) red[tid >> 6] = ss;
  __syncthreads();
  float r = rsqrtf((red[0] + red[1] + red[2] + red[3]) * (1.0f / HID) + 1e-5f);
  float4 wv = ((const float4*)w)[tid];
  float nx = v.x * r * wv.x;
  float ny = v.y * r * wv.y;
  float nz = v.z * r * wv.z;
  float nw = v.w * r * wv.w;
  ushort4 o;
  o.x = f2bf(nx); o.y = f2bf(ny); o.z = f2bf(nz); o.w = f2bf(nw);
  ((ushort4*)(out + (size_t)t * HID))[tid] = o;
  if (hcopy){
    float4 hv; hv.x = nx; hv.y = ny; hv.z = nz; hv.w = nw;
    ((float4*)(hcopy + (size_t)t * HID))[tid] = hv;
  }
}

// ------- convert (QKVO, all layers): fp32 [K][N] -> bf16 W^T [N][K], chunk-XOR swizzled --
__global__ __launch_bounds__(256) void convert_w_qkvo(const float* __restrict__ W0,
                                                      const float* __restrict__ W1,
                                                      const float* __restrict__ W2,
                                                      const float* __restrict__ W3,
                                                      unsigned short* __restrict__ Wt){
  __shared__ unsigned short t_lds[64][72];
  const int z = blockIdx.z, sel = z >> 3, l = z & 7;
  const float* W = ((sel == 0) ? W0 : (sel == 1) ? W1 : (sel == 2) ? W2 : W3)
                 + (size_t)l * HID * HID;
  unsigned short* dst = Wt + (size_t)z * HID * HID;
  const int n0 = blockIdx.x * 64, k0 = blockIdx.y * 64;
  const int tid = threadIdx.x;
  const int tr = tid >> 4, tc = tid & 15;
  #pragma unroll
  for (int i = 0; i < 4; ++i){
    int kk = tr + i * 16;
    float4 v = *(const float4*)(W + (size_t)(k0 + kk) * HID + n0 + tc * 4);
    t_lds[tc*4+0][kk] = f2bf(v.x);
    t_lds[tc*4+1][kk] = f2bf(v.y);
    t_lds[tc*4+2][kk] = f2bf(v.z);
    t_lds[tc*4+3][kk] = f2bf(v.w);
  }
  __syncthreads();
  const int n = tid >> 2, cp = tid & 3;
  #pragma unroll
  for (int j = 0; j < 2; ++j){
    int c = cp * 2 + j;
    uint4 d = *(const uint4*)(&t_lds[n][c * 8]);
    *(uint4*)(dst + (size_t)(n0 + n) * HID + k0 + ((c ^ (n & 7)) << 3)) = d;
  }
}

// ------- convert (layer weights): fp32 [K][N] -> bf16 W^T [N][K], chunk-XOR swizzled ----
__global__ __launch_bounds__(256) void convert_w_swz(const float* __restrict__ W,
                                                     unsigned short* __restrict__ Wt,
                                                     int K, int N){
  __shared__ unsigned short t_lds[64][72];
  W  += (size_t)blockIdx.z * K * N;
  Wt += (size_t)blockIdx.z * K * N;
  const int n0 = blockIdx.x * 64, k0 = blockIdx.y * 64;
  const int tid = threadIdx.x;
  const int tr = tid >> 4, tc = tid & 15;
  #pragma unroll
  for (int i = 0; i < 4; ++i){
    int kk = tr + i * 16;
    float4 v = *(const float4*)(W + (size_t)(k0 + kk) * N + n0 + tc * 4);
    t_lds[tc*4+0][kk] = f2bf(v.x);
    t_lds[tc*4+1][kk] = f2bf(v.y);
    t_lds[tc*4+2][kk] = f2bf(v.z);
    t_lds[tc*4+3][kk] = f2bf(v.w);
  }
  __syncthreads();
  const int n = tid >> 2, cp = tid & 3;
  #pragma unroll
  for (int j = 0; j < 2; ++j){
    int c = cp * 2 + j;
    uint4 d = *(const uint4*)(&t_lds[n][c * 8]);
    *(uint4*)(Wt + (size_t)(n0 + n) * K + k0 + ((c ^ (n & 7)) << 3)) = d;
  }
}

// ------- convert (batched, linear): fp32 [K][N] -> bf16 W^T [N][K] linear ----------------
__global__ __launch_bounds__(256) void convert_w_linb(const float* __restrict__ W,
                                                      unsigned short* __restrict__ Wt,
                                                      int K, int N){
  __shared__ unsigned short t_lds[64][72];
  W  += (size_t)blockIdx.z * K * N;
  Wt += (size_t)blockIdx.z * K * N;
  const int n0 = blockIdx.x * 64, k0 = blockIdx.y * 64;
  const int tid = threadIdx.x;
  const int tr = tid >> 4, tc = tid & 15;
  #pragma unroll
  for (int i = 0; i < 4; ++i){
    int kk = tr + i * 16;
    float4 v = *(const float4*)(W + (size_t)(k0 + kk) * N + n0 + tc * 4);
    t_lds[tc*4+0][kk] = f2bf(v.x);
    t_lds[tc*4+1][kk] = f2bf(v.y);
    t_lds[tc*4+2][kk] = f2bf(v.z);
    t_lds[tc*4+3][kk] = f2bf(v.w);
  }
  __syncthreads();
  const int n = tid >> 2, cp = tid & 3;
  #pragma unroll
  for (int j = 0; j < 2; ++j){
    int c = cp * 2 + j;
    uint4 d = *(const uint4*)(&t_lds[n][c * 8]);
    *(uint4*)(Wt + (size_t)(n0 + n) * K + k0 + c * 8) = d;
  }
}

// ------- convert (head weight): fp32 [K][N] -> bf16 W^T [N][K] linear ----------------
__global__ __launch_bounds__(256) void convert_w_lin(const float* __restrict__ W,
                                                     unsigned short* __restrict__ Wt,
                                                     int K, int N){
  __shared__ unsigned short t_lds[64][72];
  const int n0 = blockIdx.x * 64, k0 = blockIdx.y * 64;
  const int tid = threadIdx.x;
  const int tr = tid >> 4, tc = tid & 15;
  #pragma unroll
  for (int i = 0; i < 4; ++i){
    int kk = tr + i * 16;
    float4 v = *(const float4*)(W + (size_t)(k0 + kk) * N + n0 + tc * 4);
    t_lds[tc*4+0][kk] = f2bf(v.x);
    t_lds[tc*4+1][kk] = f2bf(v.y);
    t_lds[tc*4+2][kk] = f2bf(v.z);
    t_lds[tc*4+3][kk] = f2bf(v.w);
  }
  __syncthreads();
  const int n = tid >> 2, cp = tid & 3;
  #pragma unroll
  for (int j = 0; j < 2; ++j){
    int c = cp * 2 + j;
    uint4 d = *(const uint4*)(&t_lds[n][c * 8]);
    *(uint4*)(Wt + (size_t)(n0 + n) * K + k0 + c * 8) = d;
  }
}

// ===== core A (layer GEMMs): 128x128 tile, BK=64, pre-swizzled B, swizzled A src =====
__device__ __forceinline__ void gemm_core64(const unsigned short* __restrict__ A,
                                            const unsigned short* __restrict__ Bt,
                                            int K, int m0, int n0,
                                            unsigned short* As, unsigned short* Bs,
                                            f32x4 (&acc)[4][4]){
  const int tid = threadIdx.x;
  const int lane = tid & 63, w = tid >> 6;
  const int l15 = lane & 15, g = lane >> 4;
  const int lr = lane >> 3;
  const int lc = lane & 7;
  const int wr = w >> 1, wc = w & 1;
  const int axor = ((lc ^ lr) << 3);

  #pragma unroll
  for (int m = 0; m < 4; ++m)
    #pragma unroll
    for (int n = 0; n < 4; ++n)
      #pragma unroll
      for (int i = 0; i < 4; ++i) acc[m][n][i] = 0.0f;

  for (int kk = 0; kk < K; kk += 64){
    __syncthreads();
    #pragma unroll
    for (int i = 0; i < 4; ++i){
      int rb = (i * 4 + w) * 8;
      GLOAD_LDS16(A  + (size_t)(m0 + rb + lr) * K + kk + axor,      As + rb * 64);
      GLOAD_LDS16(Bt + (size_t)(n0 + rb + lr) * K + kk + (lc << 3), Bs + rb * 64);
    }
    __syncthreads();
    short8 a[4][2], b[4][2];
    const int x = l15 & 7;
    #pragma unroll
    for (int m = 0; m < 4; ++m){
      int row = wr * 64 + m * 16 + l15;
      a[m][0] = *(const short8*)(As + row * 64 + ((g       ^ x) << 3));
      a[m][1] = *(const short8*)(As + row * 64 + (((4 + g) ^ x) << 3));
    }
    #pragma unroll
    for (int n = 0; n < 4; ++n){
      int row = wc * 64 + n * 16 + l15;
      b[n][0] = *(const short8*)(Bs + row * 64 + ((g       ^ x) << 3));
      b[n][1] = *(const short8*)(Bs + row * 64 + (((4 + g) ^ x) << 3));
    }
    #pragma unroll
    for (int m = 0; m < 4; ++m)
      #pragma unroll
      for (int n = 0; n < 4; ++n){
        acc[m][n] = __builtin_amdgcn_mfma_f32_16x16x32_bf16(a[m][0], b[n][0], acc[m][n], 0, 0, 0);
        acc[m][n] = __builtin_amdgcn_mfma_f32_16x16x32_bf16(a[m][1], b[n][1], acc[m][n], 0, 0, 0);
      }
  }
}

// MODE 0: bf16 out. MODE 1: f32 resid+acc. MODE 2: bf16 C^T. MODE 3: f32 nontemporal.
template<int MODE>
__device__ __forceinline__ void gemm_epi(const f32x4 (&acc)[4][4], void* Cout,
                                         const float* __restrict__ resid,
                                         int N, int m0, int n0, int ldt){
  const int tid = threadIdx.x;
  const int lane = tid & 63, w = tid >> 6;
  const int l15 = lane & 15, g = lane >> 4;
  const int wr = w >> 1, wc = w & 1;
  #pragma unroll
  for (int m = 0; m < 4; ++m){
    #pragma unroll
    for (int n = 0; n < 4; ++n){
      int row0 = m0 + wr * 64 + m * 16 + g * 4;
      int col  = n0 + wc * 64 + n * 16 + l15;
      #pragma unroll
      for (int i = 0; i < 4; ++i){
        float v = acc[m][n][i];
        if (MODE == 0){
          ((unsigned short*)Cout)[(size_t)(row0 + i) * N + col] = f2bf(v);
        } else if (MODE == 1){
          size_t idx = (size_t)(row0 + i) * N + col;
          ((float*)Cout)[idx] = resid[idx] + v;
        } else if (MODE == 2){
          ((unsigned short*)Cout)[(size_t)col * ldt + (row0 + i)] = f2bf(v);
        } else {
          __builtin_nontemporal_store(v, &((float*)Cout)[(size_t)(row0 + i) * N + col]);
        }
      }
    }
  }
}

// ===== O/D GEMM: 64x128 tile, BK=64, 4 waves, 2 blocks/CU at grid 512 =====
__global__ __launch_bounds__(256) void gemm_od(const unsigned short* __restrict__ A,
                                               const unsigned short* __restrict__ Bt,
                                               float* __restrict__ Cout,
                                               const float* __restrict__ resid,
                                               int K, int N){
  __shared__ unsigned short As[64 * 64];
  __shared__ unsigned short Bs[128 * 64];
  const int tid = threadIdx.x;
  const int lane = tid & 63, w = tid >> 6;
  const int l15 = lane & 15, g = lane >> 4;
  const int lr = lane >> 3, lc = lane & 7;
  const int axor = ((lc ^ lr) << 3);
  const int m0 = blockIdx.x * 64, n0 = blockIdx.y * 128;

  f32x4 acc[4][2];
  #pragma unroll
  for (int m = 0; m < 4; ++m)
    #pragma unroll
    for (int n = 0; n < 2; ++n)
      #pragma unroll
      for (int i = 0; i < 4; ++i) acc[m][n][i] = 0.0f;

  for (int kk = 0; kk < K; kk += 64){
    __syncthreads();
    #pragma unroll
    for (int i = 0; i < 2; ++i){
      int rb = (i * 4 + w) * 8;
      GLOAD_LDS16(A + (size_t)(m0 + rb + lr) * K + kk + axor, As + rb * 64);
    }
    #pragma unroll
    for (int i = 0; i < 4; ++i){
      int rb = (i * 4 + w) * 8;
      GLOAD_LDS16(Bt + (size_t)(n0 + rb + lr) * K + kk + (lc << 3), Bs + rb * 64);
    }
    __syncthreads();
    short8 a[4][2], b[2][2];
    const int x = l15 & 7;
    #pragma unroll
    for (int m = 0; m < 4; ++m){
      int row = m * 16 + l15;
      a[m][0] = *(const short8*)(As + row * 64 + ((g       ^ x) << 3));
      a[m][1] = *(const short8*)(As + row * 64 + (((4 + g) ^ x) << 3));
    }
    #pragma unroll
    for (int n = 0; n < 2; ++n){
      int row = w * 32 + n * 16 + l15;
      b[n][0] = *(const short8*)(Bs + row * 64 + ((g       ^ x) << 3));
      b[n][1] = *(const short8*)(Bs + row * 64 + (((4 + g) ^ x) << 3));
    }
    #pragma unroll
    for (int m = 0; m < 4; ++m)
      #pragma unroll
      for (int n = 0; n < 2; ++n){
        acc[m][n] = __builtin_amdgcn_mfma_f32_16x16x32_bf16(a[m][0], b[n][0], acc[m][n], 0, 0, 0);
        acc[m][n] = __builtin_amdgcn_mfma_f32_16x16x32_bf16(a[m][1], b[n][1], acc[m][n], 0, 0, 0);
      }
  }
  #pragma unroll
  for (int m = 0; m < 4; ++m)
    #pragma unroll
    for (int n = 0; n < 2; ++n){
      int row0 = m0 + m * 16 + g * 4;
      int col  = n0 + w * 32 + n * 16 + l15;
      #pragma unroll
      for (int i = 0; i < 4; ++i){
        size_t idx = (size_t)(row0 + i) * N + col;
        Cout[idx] = resid[idx] + acc[m][n][i];
      }
    }
}

// ===== 8-phase pipeline macros (shared by head8p / gusilu8p) =====
#define WAITV4 asm volatile("s_waitcnt vmcnt(4)" ::: "memory")
#define WAITV2 asm volatile("s_waitcnt vmcnt(2)" ::: "memory")
#define WAITV0 asm volatile("s_waitcnt vmcnt(0)" ::: "memory")
#define HBAR() { __builtin_amdgcn_s_barrier(); asm volatile("" ::: "memory"); }

// stage one 16KB half-tile from linear global [rows][K] with source pre-swizzle
#define STAGE_HALF(BUF, MAT, HALF, BP, KK)                                       \
{                                                                                \
  unsigned short* dbase = smem8 + ((((BUF)*2+(MAT))*2+(HALF)) << 13) + (w*8)*64; \
  const unsigned short* G = (MAT) ? (BP) : A;                                    \
  const int brc = (MAT) ? n0 : m0;                                               \
  int r0 = w*8 + lr8, r1 = r0 + 64;                                              \
  int g0, g1;                                                                    \
  if (MAT){ g0 = brc + ((r0>>5)<<6) + ((HALF)<<5) + (r0&31);                     \
            g1 = brc + ((r1>>5)<<6) + ((HALF)<<5) + (r1&31); }                   \
  else    { g0 = brc + ((r0>>6)<<7) + ((HALF)<<6) + (r0&63);                     \
            g1 = brc + ((r1>>6)<<7) + ((HALF)<<6) + (r1&63); }                   \
  GLOAD_LDS16(G + (size_t)g0*K + (KK) + axor, dbase);                            \
  GLOAD_LDS16(G + (size_t)g1*K + (KK) + axor, dbase + 64*64);                    \
}

// ===== head GEMM: 256x256 tile, 8 waves, 4-phase/K-tile counted-vmcnt pipeline =====
__global__ __launch_bounds__(512, 2) void gemm_head8p(const unsigned short* __restrict__ A,
                                                      const unsigned short* __restrict__ Bt,
                                                      float* __restrict__ out){
  __shared__ unsigned short smem8[65536];   // 128 KB: [buf][mat][half][128][64]
  const int tid = threadIdx.x;
  const int lane = tid & 63, w = tid >> 6;        // 8 waves
  const int l15 = lane & 15, g = lane >> 4;
  const int wr = w >> 2, wc = w & 3;              // 2 (M) x 4 (N)
  const int lr8 = lane >> 3, lc = lane & 7;
  const int axor = ((lc ^ lr8) << 3);             // source chunk pre-swizzle
  const int x = l15 & 7;
  const int sl0 = ((g ^ x) << 3), sl1 = (((4 + g) ^ x) << 3);
  const int m0 = blockIdx.x * 256, n0 = blockIdx.y * 256;
  const int K = HID, nt = HID / 64;               // 16 K-tiles

  f32x4 acc[8][4];
  #pragma unroll
  for (int m = 0; m < 8; ++m)
    #pragma unroll
    for (int n = 0; n < 4; ++n)
      #pragma unroll
      for (int i = 0; i < 4; ++i) acc[m][n][i] = 0.0f;

  STAGE_HALF(0, 0, 0, Bt, 0)
  STAGE_HALF(0, 1, 0, Bt, 0)
  STAGE_HALF(0, 1, 1, Bt, 0)
  STAGE_HALF(0, 0, 1, Bt, 0)
  WAITV4;
  HBAR();

  for (int t = 0; t < nt; ++t){
    const int buf = t & 1, sb = buf ^ 1;
    const int kkn = (t + 1) * 64;
    const bool st = (t + 1 < nt);
    const int aB0 = ((buf*2+0)*2+0) << 13;
    const int aB1 = aB0 + 8192;
    const int bB0 = ((buf*2+1)*2+0) << 13;
    const int bB1 = bB0 + 8192;
    short8 a[4][2], b0[2][2], b1[2][2];

    // ---- phase 0: A0 x B0 ----
    #pragma unroll
    for (int m4 = 0; m4 < 4; ++m4){
      const unsigned short* p = smem8 + aB0 + (wr*64 + m4*16 + l15) * 64;
      a[m4][0] = *(const short8*)(p + sl0);
      a[m4][1] = *(const short8*)(p + sl1);
    }
    #pragma unroll
    for (int n2 = 0; n2 < 2; ++n2){
      const unsigned short* p = smem8 + bB0 + (wc*32 + n2*16 + l15) * 64;
      b0[n2][0] = *(const short8*)(p + sl0);
      b0[n2][1] = *(const short8*)(p + sl1);
    }
    if (st){ STAGE_HALF(sb, 0, 0, Bt, kkn) }
    HBAR();
    __builtin_amdgcn_s_setprio(1);
    #pragma unroll
    for (int m4 = 0; m4 < 4; ++m4)
      #pragma unroll
      for (int n2 = 0; n2 < 2; ++n2){
        acc[m4][n2] = __builtin_amdgcn_mfma_f32_16x16x32_bf16(a[m4][0], b0[n2][0], acc[m4][n2], 0, 0, 0);
        acc[m4][n2] = __builtin_amdgcn_mfma_f32_16x16x32_bf16(a[m4][1], b0[n2][1], acc[m4][n2], 0, 0, 0);
      }
    __builtin_amdgcn_s_setprio(0);
    if (st){ WAITV4; } else { WAITV2; }
    HBAR();

    // ---- phase 1: A0 x B1 ----
    #pragma unroll
    for (int n2 = 0; n2 < 2; ++n2){
      const unsigned short* p = smem8 + bB1 + (wc*32 + n2*16 + l15) * 64;
      b1[n2][0] = *(const short8*)(p + sl0);
      b1[n2][1] = *(const short8*)(p + sl1);
    }
    if (st){ STAGE_HALF(sb, 1, 0, Bt, kkn) }
    HBAR();
    __builtin_amdgcn_s_setprio(1);
    #pragma unroll
    for (int m4 = 0; m4 < 4; ++m4)
      #pragma unroll
      for (int n2 = 0; n2 < 2; ++n2){
        acc[m4][2+n2] = __builtin_amdgcn_mfma_f32_16x16x32_bf16(a[m4][0], b1[n2][0], acc[m4][2+n2], 0, 0, 0);
        acc[m4][2+n2] = __builtin_amdgcn_mfma_f32_16x16x32_bf16(a[m4][1], b1[n2][1], acc[m4][2+n2], 0, 0, 0);
      }
    __builtin_amdgcn_s_setprio(0);
    if (st){ WAITV4; } else { WAITV0; }
    HBAR();

    // ---- phase 2: A1 x B0 ----
    #pragma unroll
    for (int m4 = 0; m4 < 4; ++m4){
      const unsigned short* p = smem8 + aB1 + (wr*64 + m4*16 + l15) * 64;
      a[m4][0] = *(const short8*)(p + sl0);
      a[m4][1] = *(const short8*)(p + sl1);
    }
    if (st){ STAGE_HALF(sb, 1, 1, Bt, kkn) }
    HBAR();
    __builtin_amdgcn_s_setprio(1);
    #pragma unroll
    for (int m4 = 0; m4 < 4; ++m4)
      #pragma unroll
      for (int n2 = 0; n2 < 2; ++n2){
        acc[4+m4][n2] = __builtin_amdgcn_mfma_f32_16x16x32_bf16(a[m4][0], b0[n2][0], acc[4+m4][n2], 0, 0, 0);
        acc[4+m4][n2] = __builtin_amdgcn_mfma_f32_16x16x32_bf16(a[m4][1], b0[n2][1], acc[4+m4][n2], 0, 0, 0);
      }
    __builtin_amdgcn_s_setprio(0);
    HBAR();

    // ---- phase 3: A1 x B1 ----
    if (st){ STAGE_HALF(sb, 0, 1, Bt, kkn) }
    HBAR();
    __builtin_amdgcn_s_setprio(1);
    #pragma unroll
    for (int m4 = 0; m4 < 4; ++m4)
      #pragma unroll
      for (int n2 = 0; n2 < 2; ++n2){
        acc[4+m4][2+n2] = __builtin_amdgcn_mfma_f32_16x16x32_bf16(a[m4][0], b1[n2][0], acc[4+m4][2+n2], 0, 0, 0);
        acc[4+m4][2+n2] = __builtin_amdgcn_mfma_f32_16x16x32_bf16(a[m4][1], b1[n2][1], acc[4+m4][2+n2], 0, 0, 0);
      }
    __builtin_amdgcn_s_setprio(0);
    if (st){ WAITV4; }
    HBAR();
  }

  #pragma unroll
  for (int m = 0; m < 8; ++m)
    #pragma unroll
    for (int n = 0; n < 4; ++n){
      int row0 = m0 + wr*128 + m*16 + g*4;
      int col  = n0 + wc*64  + n*16 + l15;
      #pragma unroll
      for (int i = 0; i < 4; ++i)
        __builtin_nontemporal_store(acc[m][n][i], &out[(size_t)(row0 + i) * VOCAB + col]);
    }
}

// ===== gate+up+silu: 8-phase pipeline, virtual K=2048 (G tiles 0-15, U tiles 16-31) =====
// G accumulator stashed to gb (bf16, per-thread private) at the boundary, read back in
// the epilogue. Linear WtG/WtU layout (STAGE applies its own source swizzle).
__global__ __launch_bounds__(512, 2) void gemm_gusilu8p(const unsigned short* __restrict__ A,
                                                        const unsigned short* __restrict__ BtG,
                                                        const unsigned short* __restrict__ BtU,
                                                        unsigned short* __restrict__ gb){
  __shared__ unsigned short smem8[65536];
  const int tid = threadIdx.x;
  const int lane = tid & 63, w = tid >> 6;
  const int l15 = lane & 15, g = lane >> 4;
  const int wr = w >> 2, wc = w & 3;
  const int lr8 = lane >> 3, lc = lane & 7;
  const int axor = ((lc ^ lr8) << 3);
  const int x = l15 & 7;
  const int sl0 = ((g ^ x) << 3), sl1 = (((4 + g) ^ x) << 3);
  const int m0 = blockIdx.x * 256, n0 = blockIdx.y * 256;
  const int K = HID;
  const int nt2 = 32;                       // 16 G-tiles + 16 U-tiles

  f32x4 acc[8][4];
  #pragma unroll
  for (int m = 0; m < 8; ++m)
    #pragma unroll
    for (int n = 0; n < 4; ++n)
      #pragma unroll
      for (int i = 0; i < 4; ++i) acc[m][n][i] = 0.0f;

  STAGE_HALF(0, 0, 0, BtG, 0)
  STAGE_HALF(0, 1, 0, BtG, 0)
  STAGE_HALF(0, 1, 1, BtG, 0)
  STAGE_HALF(0, 0, 1, BtG, 0)
  WAITV4;
  HBAR();

  for (int t = 0; t < nt2; ++t){
    // G done after tile 15's phases: stash to gb (private round-trip), reset acc
    if (t == 16){
      #pragma unroll
      for (int m = 0; m < 8; ++m)
        #pragma unroll
        for (int n = 0; n < 4; ++n){
          int row0 = m0 + wr*128 + m*16 + g*4;
          int col  = n0 + wc*64  + n*16 + l15;
          #pragma unroll
          for (int i = 0; i < 4; ++i){
            gb[(size_t)(row0 + i) * INTER + col] = f2bf(acc[m][n][i]);
            acc[m][n][i] = 0.0f;
          }
        }
    }
    const int buf = t & 1, sb = buf ^ 1;
    const int tn = t + 1;
    const bool st = (tn < nt2);
    const unsigned short* Bn = (tn < 16) ? BtG : BtU;
    const int kkn = (tn & 15) * 64;
    const int aB0 = ((buf*2+0)*2+0) << 13;
    const int aB1 = aB0 + 8192;
    const int bB0 = ((buf*2+1)*2+0) << 13;
    const int bB1 = bB0 + 8192;
    short8 a[4][2], b0[2][2], b1[2][2];

    // ---- phase 0: A0 x B0 ----
    #pragma unroll
    for (int m4 = 0; m4 < 4; ++m4){
      const unsigned short* p = smem8 + aB0 + (wr*64 + m4*16 + l15) * 64;
      a[m4][0] = *(const short8*)(p + sl0);
      a[m4][1] = *(const short8*)(p + sl1);
    }
    #pragma unroll
    for (int n2 = 0; n2 < 2; ++n2){
      const unsigned short* p = smem8 + bB0 + (wc*32 + n2*16 + l15) * 64;
      b0[n2][0] = *(const short8*)(p + sl0);
      b0[n2][1] = *(const short8*)(p + sl1);
    }
    if (st){ STAGE_HALF(sb, 0, 0, Bn, kkn) }
    HBAR();
    __builtin_amdgcn_s_setprio(1);
    #pragma unroll
    for (int m4 = 0; m4 < 4; ++m4)
      #pragma unroll
      for (int n2 = 0; n2 < 2; ++n2){
        acc[m4][n2] = __builtin_amdgcn_mfma_f32_16x16x32_bf16(a[m4][0], b0[n2][0], acc[m4][n2], 0, 0, 0);
        acc[m4][n2] = __builtin_amdgcn_mfma_f32_16x16x32_bf16(a[m4][1], b0[n2][1], acc[m4][n2], 0, 0, 0);
      }
    __builtin_amdgcn_s_setprio(0);
    if (st){ WAITV4; } else { WAITV2; }
    HBAR();

    // ---- phase 1: A0 x B1 ----
    #pragma unroll
    for (int n2 = 0; n2 < 2; ++n2){
      const unsigned short* p = smem8 + bB1 + (wc*32 + n2*16 + l15) * 64;
      b1[n2][0] = *(const short8*)(p + sl0);
      b1[n2][1] = *(const short8*)(p + sl1);
    }
    if (st){ STAGE_HALF(sb, 1, 0, Bn, kkn) }
    HBAR();
    __builtin_amdgcn_s_setprio(1);
    #pragma unroll
    for (int m4 = 0; m4 < 4; ++m4)
      #pragma unroll
      for (int n2 = 0; n2 < 2; ++n2){
        acc[m4][2+n2] = __builtin_amdgcn_mfma_f32_16x16x32_bf16(a[m4][0], b1[n2][0], acc[m4][2+n2], 0, 0, 0);
        acc[m4][2+n2] = __builtin_amdgcn_mfma_f32_16x16x32_bf16(a[m4][1], b1[n2][1], acc[m4][2+n2], 0, 0, 0);
      }
    __builtin_amdgcn_s_setprio(0);
    if (st){ WAITV4; } else { WAITV0; }
    HBAR();

    // ---- phase 2: A1 x B0 ----
    #pragma unroll
    for (int m4 = 0; m4 < 4; ++m4){
      const unsigned short* p = smem8 + aB1 + (wr*64 + m4*16 + l15) * 64;
      a[m4][0] = *(const short8*)(p + sl0);
      a[m4][1] = *(const short8*)(p + sl1);
    }
    if (st){ STAGE_HALF(sb, 1, 1, Bn, kkn) }
    HBAR();
    __builtin_amdgcn_s_setprio(1);
    #pragma unroll
    for (int m4 = 0; m4 < 4; ++m4)
      #pragma unroll
      for (int n2 = 0; n2 < 2; ++n2){
        acc[4+m4][n2] = __builtin_amdgcn_mfma_f32_16x16x32_bf16(a[m4][0], b0[n2][0], acc[4+m4][n2], 0, 0, 0);
        acc[4+m4][n2] = __builtin_amdgcn_mfma_f32_16x16x32_bf16(a[m4][1], b0[n2][1], acc[4+m4][n2], 0, 0, 0);
      }
    __builtin_amdgcn_s_setprio(0);
    HBAR();

    // ---- phase 3: A1 x B1 ----
    if (st){ STAGE_HALF(sb, 0, 1, Bn, kkn) }
    HBAR();
    __builtin_amdgcn_s_setprio(1);
    #pragma unroll
    for (int m4 = 0; m4 < 4; ++m4)
      #pragma unroll
      for (int n2 = 0; n2 < 2; ++n2){
        acc[4+m4][2+n2] = __builtin_amdgcn_mfma_f32_16x16x32_bf16(a[m4][0], b1[n2][0], acc[4+m4][2+n2], 0, 0, 0);
        acc[4+m4][2+n2] = __builtin_amdgcn_mfma_f32_16x16x32_bf16(a[m4][1], b1[n2][1], acc[4+m4][2+n2], 0, 0, 0);
      }
    __builtin_amdgcn_s_setprio(0);
    if (st){ WAITV4; }
    HBAR();
  }

  // epilogue: silu(gate) * up -> gb
  #pragma unroll
  for (int m = 0; m < 8; ++m)
    #pragma unroll
    for (int n = 0; n < 4; ++n){
      int row0 = m0 + wr*128 + m*16 + g*4;
      int col  = n0 + wc*64  + n*16 + l15;
      #pragma unroll
      for (int i = 0; i < 4; ++i){
        size_t idx = (size_t)(row0 + i) * INTER + col;
        float gv = bf2f(gb[idx]);
        float s  = (gv / (1.0f + __expf(-gv))) * acc[m][n][i];
        gb[idx] = f2bf(s);
      }
    }
}

// fused QKV + RoPE epilogue: grid.y = 24 (8 q | 8 k | 8 v-transposed)
__global__ __launch_bounds__(256) void gemm_qkv(const unsigned short* __restrict__ A,
                                                const unsigned short* __restrict__ BtQ,
                                                const unsigned short* __restrict__ BtK,
                                                const unsigned short* __restrict__ BtV,
                                                unsigned short* qb, unsigned short* kb,
                                                unsigned short* vt,
                                                const float* __restrict__ cosT,
                                                const float* __restrict__ sinT){
  __shared__ unsigned short As[128 * 64];
  __shared__ unsigned short Bs[128 * 64];
  const int nb = blockIdx.y, sel = nb >> 3, n0 = (nb & 7) * 128;
  const unsigned short* Bt = (sel == 0) ? BtQ : (sel == 1) ? BtK : BtV;
  f32x4 acc[4][4];
  gemm_core64(A, Bt, HID, blockIdx.x * 128, n0, As, Bs, acc);
  if (sel == 2){
    gemm_epi<2>(acc, vt, nullptr, HID, blockIdx.x * 128, n0, T_TOK);
    return;
  }
  unsigned short* outp = sel ? kb : qb;
  const float qs = sel ? 1.0f : 0.125f;
  const int tid = threadIdx.x;
  const int lane = tid & 63, w = tid >> 6;
  const int l15 = lane & 15, g = lane >> 4;
  const int wr = w >> 1, wc = w & 1;
  const int m0 = blockIdx.x * 128;
  #pragma unroll
  for (int m = 0; m < 4; ++m){
    #pragma unroll
    for (int n = 0; n < 2; ++n){
      int row0 = m0 + wr * 64 + m * 16 + g * 4;
      int col  = n0 + wc * 64 + n * 16 + l15;
      int f    = (col & 63);
      #pragma unroll
      for (int i = 0; i < 4; ++i){
        int t = row0 + i, s = t & (SEQ - 1);
        float c  = cosT[s * 32 + f];
        float sn = sinT[s * 32 + f];
        float x0 = acc[m][n][i], x1 = acc[m][n + 2][i];
        outp[(size_t)t * HID + col]      = f2bf((x0 * c - x1 * sn) * qs);
        outp[(size_t)t * HID + col + 32] = f2bf((x1 * c + x0 * sn) * qs);
      }
    }
  }
}

// ---------------- fallback GEMM with fp32 B (head only, if ws too small) ----------------
__global__ __launch_bounds__(256, 2) void gemm_f32b(const unsigned short* __restrict__ A,
                                                    const float* __restrict__ Bw,
                                                    float* __restrict__ Cout,
                                                    int M, int N, int K){
  __shared__ unsigned short As[128 * 32];
  __shared__ unsigned short Bs[128 * 32];
  const int tid = threadIdx.x;
  const int lane = tid & 63, wid = tid >> 6;
  const int l15 = lane & 15, g = lane >> 4;
  const int wr = wid >> 1, wc = wid & 1;
  const int m0 = blockIdx.x * 128, n0 = blockIdx.y * 128;
  const int bcol = tid & 127, bhalf = tid >> 7;
  f32x4 acc[4][4];
  #pragma unroll
  for (int m = 0; m < 4; ++m)
    #pragma unroll
    for (int n = 0; n < 4; ++n)
      #pragma unroll
      for (int i = 0; i < 4; ++i) acc[m][n][i] = 0.0f;
  for (int kk = 0; kk < K; kk += 32){
    __syncthreads();
    #pragma unroll
    for (int cc = 0; cc < 2; ++cc){
      int c = tid + cc * 256;
      int row = c >> 2, kc = (c & 3) << 3;
      uint4 d = *(const uint4*)(A + (size_t)(m0 + row) * K + kk + kc);
      *(uint4*)(&As[row * 32 + kc]) = d;
    }
    {
      const float* bp = Bw + (size_t)(kk + bhalf * 16) * N + n0 + bcol;
      float f[16];
      #pragma unroll
      for (int j = 0; j < 16; ++j) f[j] = bp[(size_t)j * N];
      unsigned int pk[8];
      #pragma unroll
      for (int j = 0; j < 8; ++j)
        pk[j] = (unsigned int)f2bf(f[2*j]) | ((unsigned int)f2bf(f[2*j+1]) << 16);
      int sw = (bcol >> 1) & 3;
      int c0 = ((bhalf << 1)     ) ^ sw;
      int c1 = ((bhalf << 1) | 1 ) ^ sw;
      uint4 w0; w0.x = pk[0]; w0.y = pk[1]; w0.z = pk[2]; w0.w = pk[3];
      uint4 w1; w1.x = pk[4]; w1.y = pk[5]; w1.z = pk[6]; w1.w = pk[7];
      *(uint4*)(&Bs[bcol * 32 + c0 * 8]) = w0;
      *(uint4*)(&Bs[bcol * 32 + c1 * 8]) = w1;
    }
    __syncthreads();
    short8 a[4], b[4];
    #pragma unroll
    for (int m = 0; m < 4; ++m)
      a[m] = *(const short8*)(&As[(wr*64 + m*16 + l15) * 32 + g*8]);
    #pragma unroll
    for (int n = 0; n < 4; ++n){
      int col = wc*64 + n*16 + l15;
      b[n] = *(const short8*)(&Bs[col * 32 + (g ^ ((col >> 1) & 3)) * 8]);
    }
    #pragma unroll
    for (int m = 0; m < 4; ++m)
      #pragma unroll
      for (int n = 0; n < 4; ++n)
        acc[m][n] = __builtin_amdgcn_mfma_f32_16x16x32_bf16(a[m], b[n], acc[m][n], 0, 0, 0);
  }
  #pragma unroll
  for (int m = 0; m < 4; ++m)
    #pragma unroll
    for (int n = 0; n < 4; ++n){
      int row0 = m0 + wr*64 + m*16 + g*4;
      int col  = n0 + wc*64 + n*16 + l15;
      #pragma unroll
      for (int i = 0; i < 4; ++i)
        Cout[(size_t)(row0 + i) * N + col] = acc[m][n][i];
    }
}

// ------- flash attention: 8 waves/block, 16 q-rows per wave, KV tile 64 (r11-proven) ----
__global__ __launch_bounds__(512) void attn_kernel(const unsigned short* __restrict__ q,
                                                   const unsigned short* __restrict__ k,
                                                   const unsigned short* __restrict__ vt,
                                                   unsigned short* __restrict__ ctx){
  const int tid = threadIdx.x;
  const int lane = tid & 63, w = tid >> 6;      // w in [0,8)
  const int l15 = lane & 15, g = lane >> 4;
  const int bx = (int)gridDim.x - 1 - (int)blockIdx.x;  // heavy blocks first
  const int q0 = bx * 128 + w * 16;             // this wave's 16 q rows
  const int hh = blockIdx.y;
  const int tb = blockIdx.z * SEQ;

  __shared__ unsigned short Ks[64][72];    // [kv][d]
  __shared__ unsigned short Vs[64][72];    // [d][t]
  __shared__ unsigned short Ps[8][16][72]; // per-wave P round-trip

  short8 qa[2];
  #pragma unroll
  for (int kd = 0; kd < 2; ++kd)
    qa[kd] = *(const short8*)(q + (size_t)(tb + q0 + l15) * HID + hh*HD + kd*32 + g*8);

  float m_run[4], l_run[4];
  f32x4 o_acc[4];
  #pragma unroll
  for (int i = 0; i < 4; ++i){ m_run[i] = -1e30f; l_run[i] = 0.0f; }
  #pragma unroll
  for (int dt = 0; dt < 4; ++dt)
    #pragma unroll
    for (int i = 0; i < 4; ++i) o_acc[dt][i] = 0.0f;

  const int ntile = 2 * bx + 2;
  const int srow = tid >> 3, sc = (tid & 7) * 8;   // 512 threads: one uint4 each
  const unsigned short* kbase = k  + (size_t)(tb + srow) * HID + hh*HD + sc;
  const unsigned short* vbase = vt + (size_t)(hh*HD + srow) * T_TOK + tb + sc;

  for (int kt = 0; kt < ntile; ++kt){
    const int kv0 = kt * 64;
    __syncthreads();
    *(uint4*)(&Ks[srow][sc]) = *(const uint4*)(kbase + (size_t)kv0 * HID);
    *(uint4*)(&Vs[srow][sc]) = *(const uint4*)(vbase + kv0);
    __syncthreads();
    const int dq = q0 + 15 - kv0;
    const int nct = (dq < 0) ? 0 : min(4, (dq >> 4) + 1);
    if (nct <= 0) continue;                 // barrier counts stay uniform

    float pv[4][4];
    #pragma unroll
    for (int ct = 0; ct < 4; ++ct){
      if (ct < nct){
        f32x4 scv;
        #pragma unroll
        for (int i = 0; i < 4; ++i) scv[i] = 0.0f;
        scv = __builtin_amdgcn_mfma_f32_16x16x32_bf16(qa[0],
                *(const short8*)(&Ks[ct*16 + l15][g*8]), scv, 0, 0, 0);
        scv = __builtin_amdgcn_mfma_f32_16x16x32_bf16(qa[1],
                *(const short8*)(&Ks[ct*16 + l15][32 + g*8]), scv, 0, 0, 0);
        #pragma unroll
        for (int i = 0; i < 4; ++i){
          float s = fminf(fmaxf(scv[i], -1000.0f), 1000.0f);
          int row = q0 + g*4 + i;
          int col = kv0 + ct*16 + l15;
          pv[ct][i] = (col > row) ? -1e30f : s;
        }
      } else {
        #pragma unroll
        for (int i = 0; i < 4; ++i) pv[ct][i] = -1e30f;
      }
    }
    #pragma unroll
    for (int i = 0; i < 4; ++i){
      float mx = fmaxf(fmaxf(pv[0][i], pv[1][i]), fmaxf(pv[2][i], pv[3][i]));
      #pragma unroll
      for (int msk = 1; msk < 16; msk <<= 1) mx = fmaxf(mx, __shfl_xor(mx, msk));
      if (!__all(mx <= m_run[i] + 8.0f)){         // T13 defer-max
        float mnew = fmaxf(m_run[i], mx);
        float scale = __expf(m_run[i] - mnew);
        m_run[i] = mnew;
        l_run[i] *= scale;
        #pragma unroll
        for (int dt = 0; dt < 4; ++dt) o_acc[dt][i] *= scale;
      }
      float psum = 0.0f;
      #pragma unroll
      for (int ct = 0; ct < 4; ++ct){
        if (ct < nct){
          float p = __expf(pv[ct][i] - m_run[i]);
          pv[ct][i] = p; psum += p;
        } else pv[ct][i] = 0.0f;
      }
      #pragma unroll
      for (int msk = 1; msk < 16; msk <<= 1) psum += __shfl_xor(psum, msk);
      l_run[i] += psum;
    }
    #pragma unroll
    for (int ct = 0; ct < 4; ++ct)          // write all 4 (zeros beyond nct)
      #pragma unroll
      for (int i = 0; i < 4; ++i)
        Ps[w][g*4 + i][ct*16 + l15] = f2bf(pv[ct][i]);
    const int nks = (nct + 1) >> 1;
    #pragma unroll
    for (int ks = 0; ks < 2; ++ks){
      if (ks < nks){
        short8 ap = *(const short8*)(&Ps[w][l15][ks*32 + g*8]);
        #pragma unroll
        for (int dt = 0; dt < 4; ++dt){
          short8 vb = *(const short8*)(&Vs[dt*16 + l15][ks*32 + g*8]);
          o_acc[dt] = __builtin_amdgcn_mfma_f32_16x16x32_bf16(ap, vb, o_acc[dt], 0, 0, 0);
        }
      }
    }
  }
  #pragma unroll
  for (int i = 0; i < 4; ++i) l_run[i] = 1.0f / l_run[i];   // one rcp per row
  #pragma unroll
  for (int dt = 0; dt < 4; ++dt)
    #pragma unroll
    for (int i = 0; i < 4; ++i){
      float o = o_acc[dt][i] * l_run[i];
      ctx[(size_t)(tb + q0 + g*4 + i) * HID + hh*HD + dt*16 + l15] = f2bf(o);
    }
}

extern "C" void kernel_launch(void* const* d_in, const int* in_sizes, int n_in,
                              void* d_out, int out_size, void* d_ws, size_t ws_size,
                              hipStream_t stream){
  const int*   ids    = (const int*)d_in[0];
  const float* embedW = (const float*)d_in[1];
  const float* Wq = (const float*)d_in[2];
  const float* Wk = (const float*)d_in[3];
  const float* Wv = (const float*)d_in[4];
  const float* Wo = (const float*)d_in[5];
  const float* Wg = (const float*)d_in[6];
  const float* Wu = (const float*)d_in[7];
  const float* Wd = (const float*)d_in[8];
  const float* n1 = (const float*)d_in[9];
  const float* n2 = (const float*)d_in[10];
  const float* nf = (const float*)d_in[11];
  const float* Wh = (const float*)d_in[12];
  float* out = (float*)d_out;

  // d_out scratch (dead until head GEMM, which reads only ws-resident xn/WhT)
  char* scb = (char*)d_out;
  unsigned short* qb  = (unsigned short*)(scb + 0);
  unsigned short* kb  = (unsigned short*)(scb + 8388608);
  unsigned short* vtb = (unsigned short*)(scb + 16777216);   // V^T [HID][T]
  unsigned short* ctx = (unsigned short*)(scb + 25165824);
  unsigned short* gb  = (unsigned short*)(scb + 33554432);
  float* cosT = (float*)(scb + 100663296);
  float* sinT = (float*)(scb + 100925440);
  float* h_fallback   = (float*)(scb + 104857600);
  unsigned short* WtQ = (unsigned short*)(scb + 134217728);  // 16 MB (Q,K,V,O contiguous)
  unsigned short* WtK = (unsigned short*)(scb + 150994944);
  unsigned short* WtV = (unsigned short*)(scb + 167772160);
  unsigned short* WtO = (unsigned short*)(scb + 184549376);
  unsigned short* WtG = (unsigned short*)(scb + 201326592);  // 64 MB (linear)
  unsigned short* WtU = (unsigned short*)(scb + 268435456);  // 64 MB (linear)
  unsigned short* WtD = (unsigned short*)(scb + 335544320);  // 64 MB (swizzled)

  unsigned short* xn = (unsigned short*)d_ws;                // 8 MB
  float* h = (ws_size >= 25165824u) ? (float*)((char*)d_ws + 8388608) : h_fallback;
  unsigned short* WhT = (ws_size >= 90701824u)
                      ? (unsigned short*)((char*)d_ws + 25165824) : nullptr;

  // weight converts: QKVO swizzled; G/U linear (8-phase kernel swizzles at stage time);
  // D swizzled; head linear
  convert_w_qkvo<<<dim3(16, 16, 32), 256, 0, stream>>>(Wq, Wk, Wv, Wo, WtQ);
  convert_w_linb<<<dim3(64, 16, 8), 256, 0, stream>>>(Wg, WtG, HID, INTER);
  convert_w_linb<<<dim3(64, 16, 8), 256, 0, stream>>>(Wu, WtU, HID, INTER);
  convert_w_swz<<<dim3(16, 64, 8), 256, 0, stream>>>(Wd, WtD, INTER, HID);
  if (WhT)
    convert_w_lin<<<dim3(500, 16, 1), 256, 0, stream>>>(Wh, WhT, HID, VOCAB);

  embed_kernel<<<4096, 256, 0, stream>>>(ids, embedW, h);
  rope_tab_kernel<<<256, 256, 0, stream>>>(cosT, sinT);

  for (int l = 0; l < NLAYER; ++l){
    rmsnorm_kernel<<<4096, 256, 0, stream>>>(h, n1 + l*HID, xn, nullptr);
    gemm_qkv<<<dim3(32, 24), 256, 0, stream>>>(xn, WtQ + (size_t)l*HID*HID,
                                               WtK + (size_t)l*HID*HID,
                                               WtV + (size_t)l*HID*HID, qb, kb, vtb,
                                               cosT, sinT);
    attn_kernel<<<dim3(16, 16, 2), 512, 0, stream>>>(qb, kb, vtb, ctx);
    gemm_od<<<dim3(64, 8), 256, 0, stream>>>(ctx, WtO + (size_t)l*HID*HID,
                                             h, h, HID, HID);
    rmsnorm_kernel<<<4096, 256, 0, stream>>>(h, n2 + l*HID, xn, nullptr);
    gemm_gusilu8p<<<dim3(16, 16), 512, 0, stream>>>(xn, WtG + (size_t)l*HID*INTER,
                                                    WtU + (size_t)l*HID*INTER, gb);
    gemm_od<<<dim3(64, 8), 256, 0, stream>>>(gb, WtD + (size_t)l*HID*INTER,
                                             h, h, INTER, HID);
  }

  rmsnorm_kernel<<<4096, 256, 0, stream>>>(h, nf, xn, out + 131072000);
  if (WhT)
    gemm_head8p<<<dim3(16, 125), 512, 0, stream>>>(xn, WhT, out);
  else
    gemm_f32b<<<dim3(32, 250), 256, 0, stream>>>(xn, Wh, out, T_TOK, VOCAB, HID);
}

// Round 14
// 3644.418 us; speedup vs baseline: 1.1327x; 1.1327x over previous
//
#include <hip/hip_runtime.h>

#define T_TOK 4096
#define SEQ   2048
#define HID   1024
#define NH    16
#define HD    64
#define INTER 4096
#define NLAYER 8
#define VOCAB 32000

typedef short short8 __attribute__((ext_vector_type(8)));
typedef float f32x4  __attribute__((ext_vector_type(4)));

__device__ __forceinline__ unsigned short f2bf(float f){
  unsigned int u = __builtin_bit_cast(unsigned int, f);
  u += 0x7fffu + ((u >> 16) & 1u);
  return (unsigned short)(u >> 16);
}
__device__ __forceinline__ float bf2f(unsigned short b){
  unsigned int u = ((unsigned int)b) << 16;
  return __builtin_bit_cast(float, u);
}

#define GLOAD_LDS16(gsrc, ldst) \
  __builtin_amdgcn_global_load_lds((const __attribute__((address_space(1))) void*)(gsrc), \
                                   (__attribute__((address_space(3))) void*)(ldst), 16, 0, 0)

// ---------------- embedding gather ----------------
__global__ __launch_bounds__(256) void embed_kernel(const int* __restrict__ ids,
                                                    const float* __restrict__ W,
                                                    float* __restrict__ h){
  int i = blockIdx.x * 256 + threadIdx.x;   // float4 index over [T][256]
  int t = i >> 8, c = i & 255;
  ((float4*)h)[i] = ((const float4*)(W + (size_t)ids[t] * HID))[c];
}

// ---------------- rope tables ----------------
__global__ __launch_bounds__(256) void rope_tab_kernel(float* __restrict__ cosT,
                                                       float* __restrict__ sinT){
  int i = blockIdx.x * 256 + threadIdx.x;   // s*32 + f
  int s = i >> 5, f = i & 31;
  float inv = expf(-((2.0f * (float)f) / 64.0f) * logf(100000.0f));
  float ang = (float)s * inv;
  cosT[i] = cosf(ang);
  sinT[i] = sinf(ang);
}

// ---------------- rmsnorm (fp32 in -> bf16 out, optional fp32 normed copy) ----------------
__global__ __launch_bounds__(256) void rmsnorm_kernel(const float* __restrict__ h,
                                                      const float* __restrict__ w,
                                                      unsigned short* __restrict__ out,
                                                      float* hcopy){
  int t = blockIdx.x, tid = threadIdx.x;
  float4 v = ((const float4*)(h + (size_t)t * HID))[tid];
  float ss = v.x*v.x + v.y*v.y + v.z*v.z + v.w*v.w;
  #pragma unroll
  for (int m = 1; m < 64; m <<= 1) ss += __shfl_xor(ss, m);
  __shared__ float red[4];
  if ((tid & 63) == 0) red[tid >> 6] = ss;
  __syncthreads();
  float r = rsqrtf((red[0] + red[1] + red[2] + red[3]) * (1.0f / HID) + 1e-5f);
  float4 wv = ((const float4*)w)[tid];
  float nx = v.x * r * wv.x;
  float ny = v.y * r * wv.y;
  float nz = v.z * r * wv.z;
  float nw = v.w * r * wv.w;
  ushort4 o;
  o.x = f2bf(nx); o.y = f2bf(ny); o.z = f2bf(nz); o.w = f2bf(nw);
  ((ushort4*)(out + (size_t)t * HID))[tid] = o;
  if (hcopy){
    float4 hv; hv.x = nx; hv.y = ny; hv.z = nz; hv.w = nw;
    ((float4*)(hcopy + (size_t)t * HID))[tid] = hv;
  }
}

// ------- convert (QKVO, all layers): fp32 [K][N] -> bf16 W^T [N][K], chunk-XOR swizzled --
__global__ __launch_bounds__(256) void convert_w_qkvo(const float* __restrict__ W0,
                                                      const float* __restrict__ W1,
                                                      const float* __restrict__ W2,
                                                      const float* __restrict__ W3,
                                                      unsigned short* __restrict__ Wt){
  __shared__ unsigned short t_lds[64][72];
  const int z = blockIdx.z, sel = z >> 3, l = z & 7;
  const float* W = ((sel == 0) ? W0 : (sel == 1) ? W1 : (sel == 2) ? W2 : W3)
                 + (size_t)l * HID * HID;
  unsigned short* dst = Wt + (size_t)z * HID * HID;
  const int n0 = blockIdx.x * 64, k0 = blockIdx.y * 64;
  const int tid = threadIdx.x;
  const int tr = tid >> 4, tc = tid & 15;
  #pragma unroll
  for (int i = 0; i < 4; ++i){
    int kk = tr + i * 16;
    float4 v = *(const float4*)(W + (size_t)(k0 + kk) * HID + n0 + tc * 4);
    t_lds[tc*4+0][kk] = f2bf(v.x);
    t_lds[tc*4+1][kk] = f2bf(v.y);
    t_lds[tc*4+2][kk] = f2bf(v.z);
    t_lds[tc*4+3][kk] = f2bf(v.w);
  }
  __syncthreads();
  const int n = tid >> 2, cp = tid & 3;
  #pragma unroll
  for (int j = 0; j < 2; ++j){
    int c = cp * 2 + j;
    uint4 d = *(const uint4*)(&t_lds[n][c * 8]);
    *(uint4*)(dst + (size_t)(n0 + n) * HID + k0 + ((c ^ (n & 7)) << 3)) = d;
  }
}

// ------- convert (layer weights): fp32 [K][N] -> bf16 W^T [N][K], chunk-XOR swizzled ----
__global__ __launch_bounds__(256) void convert_w_swz(const float* __restrict__ W,
                                                     unsigned short* __restrict__ Wt,
                                                     int K, int N){
  __shared__ unsigned short t_lds[64][72];
  W  += (size_t)blockIdx.z * K * N;
  Wt += (size_t)blockIdx.z * K * N;
  const int n0 = blockIdx.x * 64, k0 = blockIdx.y * 64;
  const int tid = threadIdx.x;
  const int tr = tid >> 4, tc = tid & 15;
  #pragma unroll
  for (int i = 0; i < 4; ++i){
    int kk = tr + i * 16;
    float4 v = *(const float4*)(W + (size_t)(k0 + kk) * N + n0 + tc * 4);
    t_lds[tc*4+0][kk] = f2bf(v.x);
    t_lds[tc*4+1][kk] = f2bf(v.y);
    t_lds[tc*4+2][kk] = f2bf(v.z);
    t_lds[tc*4+3][kk] = f2bf(v.w);
  }
  __syncthreads();
  const int n = tid >> 2, cp = tid & 3;
  #pragma unroll
  for (int j = 0; j < 2; ++j){
    int c = cp * 2 + j;
    uint4 d = *(const uint4*)(&t_lds[n][c * 8]);
    *(uint4*)(Wt + (size_t)(n0 + n) * K + k0 + ((c ^ (n & 7)) << 3)) = d;
  }
}

// ------- convert (head weight): fp32 [K][N] -> bf16 W^T [N][K] linear ----------------
__global__ __launch_bounds__(256) void convert_w_lin(const float* __restrict__ W,
                                                     unsigned short* __restrict__ Wt,
                                                     int K, int N){
  __shared__ unsigned short t_lds[64][72];
  const int n0 = blockIdx.x * 64, k0 = blockIdx.y * 64;
  const int tid = threadIdx.x;
  const int tr = tid >> 4, tc = tid & 15;
  #pragma unroll
  for (int i = 0; i < 4; ++i){
    int kk = tr + i * 16;
    float4 v = *(const float4*)(W + (size_t)(k0 + kk) * N + n0 + tc * 4);
    t_lds[tc*4+0][kk] = f2bf(v.x);
    t_lds[tc*4+1][kk] = f2bf(v.y);
    t_lds[tc*4+2][kk] = f2bf(v.z);
    t_lds[tc*4+3][kk] = f2bf(v.w);
  }
  __syncthreads();
  const int n = tid >> 2, cp = tid & 3;
  #pragma unroll
  for (int j = 0; j < 2; ++j){
    int c = cp * 2 + j;
    uint4 d = *(const uint4*)(&t_lds[n][c * 8]);
    *(uint4*)(Wt + (size_t)(n0 + n) * K + k0 + c * 8) = d;
  }
}

// ===== core A (layer GEMMs): 128x128 tile, BK=64, pre-swizzled B, swizzled A src =====
__device__ __forceinline__ void gemm_core64(const unsigned short* __restrict__ A,
                                            const unsigned short* __restrict__ Bt,
                                            int K, int m0, int n0,
                                            unsigned short* As, unsigned short* Bs,
                                            f32x4 (&acc)[4][4]){
  const int tid = threadIdx.x;
  const int lane = tid & 63, w = tid >> 6;
  const int l15 = lane & 15, g = lane >> 4;
  const int lr = lane >> 3;
  const int lc = lane & 7;
  const int wr = w >> 1, wc = w & 1;
  const int axor = ((lc ^ lr) << 3);

  #pragma unroll
  for (int m = 0; m < 4; ++m)
    #pragma unroll
    for (int n = 0; n < 4; ++n)
      #pragma unroll
      for (int i = 0; i < 4; ++i) acc[m][n][i] = 0.0f;

  for (int kk = 0; kk < K; kk += 64){
    __syncthreads();
    #pragma unroll
    for (int i = 0; i < 4; ++i){
      int rb = (i * 4 + w) * 8;
      GLOAD_LDS16(A  + (size_t)(m0 + rb + lr) * K + kk + axor,      As + rb * 64);
      GLOAD_LDS16(Bt + (size_t)(n0 + rb + lr) * K + kk + (lc << 3), Bs + rb * 64);
    }
    __syncthreads();
    short8 a[4][2], b[4][2];
    const int x = l15 & 7;
    #pragma unroll
    for (int m = 0; m < 4; ++m){
      int row = wr * 64 + m * 16 + l15;
      a[m][0] = *(const short8*)(As + row * 64 + ((g       ^ x) << 3));
      a[m][1] = *(const short8*)(As + row * 64 + (((4 + g) ^ x) << 3));
    }
    #pragma unroll
    for (int n = 0; n < 4; ++n){
      int row = wc * 64 + n * 16 + l15;
      b[n][0] = *(const short8*)(Bs + row * 64 + ((g       ^ x) << 3));
      b[n][1] = *(const short8*)(Bs + row * 64 + (((4 + g) ^ x) << 3));
    }
    #pragma unroll
    for (int m = 0; m < 4; ++m)
      #pragma unroll
      for (int n = 0; n < 4; ++n){
        acc[m][n] = __builtin_amdgcn_mfma_f32_16x16x32_bf16(a[m][0], b[n][0], acc[m][n], 0, 0, 0);
        acc[m][n] = __builtin_amdgcn_mfma_f32_16x16x32_bf16(a[m][1], b[n][1], acc[m][n], 0, 0, 0);
      }
  }
}

// MODE 0: bf16 out. MODE 1: f32 resid+acc. MODE 2: bf16 C^T. MODE 3: f32 nontemporal.
template<int MODE>
__device__ __forceinline__ void gemm_epi(const f32x4 (&acc)[4][4], void* Cout,
                                         const float* __restrict__ resid,
                                         int N, int m0, int n0, int ldt){
  const int tid = threadIdx.x;
  const int lane = tid & 63, w = tid >> 6;
  const int l15 = lane & 15, g = lane >> 4;
  const int wr = w >> 1, wc = w & 1;
  #pragma unroll
  for (int m = 0; m < 4; ++m){
    #pragma unroll
    for (int n = 0; n < 4; ++n){
      int row0 = m0 + wr * 64 + m * 16 + g * 4;
      int col  = n0 + wc * 64 + n * 16 + l15;
      #pragma unroll
      for (int i = 0; i < 4; ++i){
        float v = acc[m][n][i];
        if (MODE == 0){
          ((unsigned short*)Cout)[(size_t)(row0 + i) * N + col] = f2bf(v);
        } else if (MODE == 1){
          size_t idx = (size_t)(row0 + i) * N + col;
          ((float*)Cout)[idx] = resid[idx] + v;
        } else if (MODE == 2){
          ((unsigned short*)Cout)[(size_t)col * ldt + (row0 + i)] = f2bf(v);
        } else {
          __builtin_nontemporal_store(v, &((float*)Cout)[(size_t)(row0 + i) * N + col]);
        }
      }
    }
  }
}

// ===== O/D GEMM: 64x128 tile, BK=64, 4 waves, 2 blocks/CU at grid 512 =====
__global__ __launch_bounds__(256) void gemm_od(const unsigned short* __restrict__ A,
                                               const unsigned short* __restrict__ Bt,
                                               float* __restrict__ Cout,
                                               const float* __restrict__ resid,
                                               int K, int N){
  __shared__ unsigned short As[64 * 64];
  __shared__ unsigned short Bs[128 * 64];
  const int tid = threadIdx.x;
  const int lane = tid & 63, w = tid >> 6;
  const int l15 = lane & 15, g = lane >> 4;
  const int lr = lane >> 3, lc = lane & 7;
  const int axor = ((lc ^ lr) << 3);
  const int m0 = blockIdx.x * 64, n0 = blockIdx.y * 128;

  f32x4 acc[4][2];
  #pragma unroll
  for (int m = 0; m < 4; ++m)
    #pragma unroll
    for (int n = 0; n < 2; ++n)
      #pragma unroll
      for (int i = 0; i < 4; ++i) acc[m][n][i] = 0.0f;

  for (int kk = 0; kk < K; kk += 64){
    __syncthreads();
    #pragma unroll
    for (int i = 0; i < 2; ++i){
      int rb = (i * 4 + w) * 8;
      GLOAD_LDS16(A + (size_t)(m0 + rb + lr) * K + kk + axor, As + rb * 64);
    }
    #pragma unroll
    for (int i = 0; i < 4; ++i){
      int rb = (i * 4 + w) * 8;
      GLOAD_LDS16(Bt + (size_t)(n0 + rb + lr) * K + kk + (lc << 3), Bs + rb * 64);
    }
    __syncthreads();
    short8 a[4][2], b[2][2];
    const int x = l15 & 7;
    #pragma unroll
    for (int m = 0; m < 4; ++m){
      int row = m * 16 + l15;
      a[m][0] = *(const short8*)(As + row * 64 + ((g       ^ x) << 3));
      a[m][1] = *(const short8*)(As + row * 64 + (((4 + g) ^ x) << 3));
    }
    #pragma unroll
    for (int n = 0; n < 2; ++n){
      int row = w * 32 + n * 16 + l15;
      b[n][0] = *(const short8*)(Bs + row * 64 + ((g       ^ x) << 3));
      b[n][1] = *(const short8*)(Bs + row * 64 + (((4 + g) ^ x) << 3));
    }
    #pragma unroll
    for (int m = 0; m < 4; ++m)
      #pragma unroll
      for (int n = 0; n < 2; ++n){
        acc[m][n] = __builtin_amdgcn_mfma_f32_16x16x32_bf16(a[m][0], b[n][0], acc[m][n], 0, 0, 0);
        acc[m][n] = __builtin_amdgcn_mfma_f32_16x16x32_bf16(a[m][1], b[n][1], acc[m][n], 0, 0, 0);
      }
  }
  #pragma unroll
  for (int m = 0; m < 4; ++m)
    #pragma unroll
    for (int n = 0; n < 2; ++n){
      int row0 = m0 + m * 16 + g * 4;
      int col  = n0 + w * 32 + n * 16 + l15;
      #pragma unroll
      for (int i = 0; i < 4; ++i){
        size_t idx = (size_t)(row0 + i) * N + col;
        Cout[idx] = resid[idx] + acc[m][n][i];
      }
    }
}

// ===== head GEMM: 256x256 tile, 8 waves, 4-phase/K-tile counted-vmcnt pipeline =====
#define WAITV4 asm volatile("s_waitcnt vmcnt(4)" ::: "memory")
#define WAITV2 asm volatile("s_waitcnt vmcnt(2)" ::: "memory")
#define WAITV0 asm volatile("s_waitcnt vmcnt(0)" ::: "memory")
#define HBAR() { __builtin_amdgcn_s_barrier(); asm volatile("" ::: "memory"); }

__global__ __launch_bounds__(512, 2) void gemm_head8p(const unsigned short* __restrict__ A,
                                                      const unsigned short* __restrict__ Bt,
                                                      float* __restrict__ out){
  __shared__ unsigned short smem8[65536];   // 128 KB: [buf][mat][half][128][64]
  const int tid = threadIdx.x;
  const int lane = tid & 63, w = tid >> 6;        // 8 waves
  const int l15 = lane & 15, g = lane >> 4;
  const int wr = w >> 2, wc = w & 3;              // 2 (M) x 4 (N)
  const int lr8 = lane >> 3, lc = lane & 7;
  const int axor = ((lc ^ lr8) << 3);             // source chunk pre-swizzle
  const int x = l15 & 7;
  const int sl0 = ((g ^ x) << 3), sl1 = (((4 + g) ^ x) << 3);  // read slots (row&7 == x)
  const int m0 = blockIdx.x * 256, n0 = blockIdx.y * 256;
  const int K = HID, nt = HID / 64;               // 16 K-tiles

  f32x4 acc[8][4];
  #pragma unroll
  for (int m = 0; m < 8; ++m)
    #pragma unroll
    for (int n = 0; n < 4; ++n)
      #pragma unroll
      for (int i = 0; i < 4; ++i) acc[m][n][i] = 0.0f;

  #define STAGE_HALF(BUF, MAT, HALF, KK)                                           \
  {                                                                                \
    unsigned short* dbase = smem8 + ((((BUF)*2+(MAT))*2+(HALF)) << 13) + (w*8)*64; \
    const unsigned short* G = (MAT) ? Bt : A;                                      \
    const int brc = (MAT) ? n0 : m0;                                               \
    int r0 = w*8 + lr8, r1 = r0 + 64;                                              \
    int g0, g1;                                                                    \
    if (MAT){ g0 = brc + ((r0>>5)<<6) + ((HALF)<<5) + (r0&31);                     \
              g1 = brc + ((r1>>5)<<6) + ((HALF)<<5) + (r1&31); }                   \
    else    { g0 = brc + ((r0>>6)<<7) + ((HALF)<<6) + (r0&63);                     \
              g1 = brc + ((r1>>6)<<7) + ((HALF)<<6) + (r1&63); }                   \
    GLOAD_LDS16(G + (size_t)g0*K + (KK) + axor, dbase);                            \
    GLOAD_LDS16(G + (size_t)g1*K + (KK) + axor, dbase + 64*64);                    \
  }

  STAGE_HALF(0, 0, 0, 0)
  STAGE_HALF(0, 1, 0, 0)
  STAGE_HALF(0, 1, 1, 0)
  STAGE_HALF(0, 0, 1, 0)
  WAITV4;
  HBAR();

  for (int t = 0; t < nt; ++t){
    const int buf = t & 1, sb = buf ^ 1;
    const int kkn = (t + 1) * 64;
    const bool st = (t + 1 < nt);
    const int aB0 = ((buf*2+0)*2+0) << 13;
    const int aB1 = aB0 + 8192;
    const int bB0 = ((buf*2+1)*2+0) << 13;
    const int bB1 = bB0 + 8192;
    short8 a[4][2], b0[2][2], b1[2][2];

    // ---- phase 0: A0 x B0 ----
    #pragma unroll
    for (int m4 = 0; m4 < 4; ++m4){
      const unsigned short* p = smem8 + aB0 + (wr*64 + m4*16 + l15) * 64;
      a[m4][0] = *(const short8*)(p + sl0);
      a[m4][1] = *(const short8*)(p + sl1);
    }
    #pragma unroll
    for (int n2 = 0; n2 < 2; ++n2){
      const unsigned short* p = smem8 + bB0 + (wc*32 + n2*16 + l15) * 64;
      b0[n2][0] = *(const short8*)(p + sl0);
      b0[n2][1] = *(const short8*)(p + sl1);
    }
    if (st){ STAGE_HALF(sb, 0, 0, kkn) }
    HBAR();
    __builtin_amdgcn_s_setprio(1);
    #pragma unroll
    for (int m4 = 0; m4 < 4; ++m4)
      #pragma unroll
      for (int n2 = 0; n2 < 2; ++n2){
        acc[m4][n2] = __builtin_amdgcn_mfma_f32_16x16x32_bf16(a[m4][0], b0[n2][0], acc[m4][n2], 0, 0, 0);
        acc[m4][n2] = __builtin_amdgcn_mfma_f32_16x16x32_bf16(a[m4][1], b0[n2][1], acc[m4][n2], 0, 0, 0);
      }
    __builtin_amdgcn_s_setprio(0);
    if (st){ WAITV4; } else { WAITV2; }
    HBAR();

    // ---- phase 1: A0 x B1 ----
    #pragma unroll
    for (int n2 = 0; n2 < 2; ++n2){
      const unsigned short* p = smem8 + bB1 + (wc*32 + n2*16 + l15) * 64;
      b1[n2][0] = *(const short8*)(p + sl0);
      b1[n2][1] = *(const short8*)(p + sl1);
    }
    if (st){ STAGE_HALF(sb, 1, 0, kkn) }
    HBAR();
    __builtin_amdgcn_s_setprio(1);
    #pragma unroll
    for (int m4 = 0; m4 < 4; ++m4)
      #pragma unroll
      for (int n2 = 0; n2 < 2; ++n2){
        acc[m4][2+n2] = __builtin_amdgcn_mfma_f32_16x16x32_bf16(a[m4][0], b1[n2][0], acc[m4][2+n2], 0, 0, 0);
        acc[m4][2+n2] = __builtin_amdgcn_mfma_f32_16x16x32_bf16(a[m4][1], b1[n2][1], acc[m4][2+n2], 0, 0, 0);
      }
    __builtin_amdgcn_s_setprio(0);
    if (st){ WAITV4; } else { WAITV0; }
    HBAR();

    // ---- phase 2: A1 x B0 ----
    #pragma unroll
    for (int m4 = 0; m4 < 4; ++m4){
      const unsigned short* p = smem8 + aB1 + (wr*64 + m4*16 + l15) * 64;
      a[m4][0] = *(const short8*)(p + sl0);
      a[m4][1] = *(const short8*)(p + sl1);
    }
    if (st){ STAGE_HALF(sb, 1, 1, kkn) }
    HBAR();
    __builtin_amdgcn_s_setprio(1);
    #pragma unroll
    for (int m4 = 0; m4 < 4; ++m4)
      #pragma unroll
      for (int n2 = 0; n2 < 2; ++n2){
        acc[4+m4][n2] = __builtin_amdgcn_mfma_f32_16x16x32_bf16(a[m4][0], b0[n2][0], acc[4+m4][n2], 0, 0, 0);
        acc[4+m4][n2] = __builtin_amdgcn_mfma_f32_16x16x32_bf16(a[m4][1], b0[n2][1], acc[4+m4][n2], 0, 0, 0);
      }
    __builtin_amdgcn_s_setprio(0);
    HBAR();

    // ---- phase 3: A1 x B1 ----
    if (st){ STAGE_HALF(sb, 0, 1, kkn) }
    HBAR();
    __builtin_amdgcn_s_setprio(1);
    #pragma unroll
    for (int m4 = 0; m4 < 4; ++m4)
      #pragma unroll
      for (int n2 = 0; n2 < 2; ++n2){
        acc[4+m4][2+n2] = __builtin_amdgcn_mfma_f32_16x16x32_bf16(a[m4][0], b1[n2][0], acc[4+m4][2+n2], 0, 0, 0);
        acc[4+m4][2+n2] = __builtin_amdgcn_mfma_f32_16x16x32_bf16(a[m4][1], b1[n2][1], acc[4+m4][2+n2], 0, 0, 0);
      }
    __builtin_amdgcn_s_setprio(0);
    if (st){ WAITV4; }
    HBAR();
  }
  #undef STAGE_HALF

  #pragma unroll
  for (int m = 0; m < 8; ++m)
    #pragma unroll
    for (int n = 0; n < 4; ++n){
      int row0 = m0 + wr*128 + m*16 + g*4;
      int col  = n0 + wc*64  + n*16 + l15;
      #pragma unroll
      for (int i = 0; i < 4; ++i)
        __builtin_nontemporal_store(acc[m][n][i], &out[(size_t)(row0 + i) * VOCAB + col]);
    }
}

// fused QKV + RoPE epilogue: grid.y = 24 (8 q | 8 k | 8 v-transposed)
__global__ __launch_bounds__(256) void gemm_qkv(const unsigned short* __restrict__ A,
                                                const unsigned short* __restrict__ BtQ,
                                                const unsigned short* __restrict__ BtK,
                                                const unsigned short* __restrict__ BtV,
                                                unsigned short* qb, unsigned short* kb,
                                                unsigned short* vt,
                                                const float* __restrict__ cosT,
                                                const float* __restrict__ sinT){
  __shared__ unsigned short As[128 * 64];
  __shared__ unsigned short Bs[128 * 64];
  const int nb = blockIdx.y, sel = nb >> 3, n0 = (nb & 7) * 128;
  const unsigned short* Bt = (sel == 0) ? BtQ : (sel == 1) ? BtK : BtV;
  f32x4 acc[4][4];
  gemm_core64(A, Bt, HID, blockIdx.x * 128, n0, As, Bs, acc);
  if (sel == 2){
    gemm_epi<2>(acc, vt, nullptr, HID, blockIdx.x * 128, n0, T_TOK);
    return;
  }
  unsigned short* outp = sel ? kb : qb;
  const float qs = sel ? 1.0f : 0.125f;
  const int tid = threadIdx.x;
  const int lane = tid & 63, w = tid >> 6;
  const int l15 = lane & 15, g = lane >> 4;
  const int wr = w >> 1, wc = w & 1;
  const int m0 = blockIdx.x * 128;
  #pragma unroll
  for (int m = 0; m < 4; ++m){
    #pragma unroll
    for (int n = 0; n < 2; ++n){
      int row0 = m0 + wr * 64 + m * 16 + g * 4;
      int col  = n0 + wc * 64 + n * 16 + l15;
      int f    = (col & 63);
      #pragma unroll
      for (int i = 0; i < 4; ++i){
        int t = row0 + i, s = t & (SEQ - 1);
        float c  = cosT[s * 32 + f];
        float sn = sinT[s * 32 + f];
        float x0 = acc[m][n][i], x1 = acc[m][n + 2][i];
        outp[(size_t)t * HID + col]      = f2bf((x0 * c - x1 * sn) * qs);
        outp[(size_t)t * HID + col + 32] = f2bf((x1 * c + x0 * sn) * qs);
      }
    }
  }
}

// fused gate+up+silu: each block computes both G and U tiles, writes silu(g)*u
__global__ __launch_bounds__(256) void gemm_gusilu(const unsigned short* __restrict__ A,
                                                   const unsigned short* __restrict__ BtG,
                                                   const unsigned short* __restrict__ BtU,
                                                   unsigned short* __restrict__ gb){
  __shared__ unsigned short As[128 * 64];
  __shared__ unsigned short Bs[128 * 64];
  const int m0 = blockIdx.x * 128, n0 = blockIdx.y * 128;
  f32x4 acc[4][4];
  gemm_core64(A, BtG, HID, m0, n0, As, Bs, acc);
  unsigned int gp[4][4][2];
  #pragma unroll
  for (int m = 0; m < 4; ++m)
    #pragma unroll
    for (int n = 0; n < 4; ++n){
      gp[m][n][0] = (unsigned int)f2bf(acc[m][n][0]) | ((unsigned int)f2bf(acc[m][n][1]) << 16);
      gp[m][n][1] = (unsigned int)f2bf(acc[m][n][2]) | ((unsigned int)f2bf(acc[m][n][3]) << 16);
    }
  gemm_core64(A, BtU, HID, m0, n0, As, Bs, acc);
  const int tid = threadIdx.x;
  const int lane = tid & 63, w = tid >> 6;
  const int l15 = lane & 15, g = lane >> 4;
  const int wr = w >> 1, wc = w & 1;
  #pragma unroll
  for (int m = 0; m < 4; ++m){
    #pragma unroll
    for (int n = 0; n < 4; ++n){
      int row0 = m0 + wr * 64 + m * 16 + g * 4;
      int col  = n0 + wc * 64 + n * 16 + l15;
      #pragma unroll
      for (int i = 0; i < 4; ++i){
        float gv = bf2f((unsigned short)(gp[m][n][i >> 1] >> ((i & 1) * 16)));
        float u  = acc[m][n][i];
        float s  = (gv / (1.0f + __expf(-gv))) * u;
        gb[(size_t)(row0 + i) * INTER + col] = f2bf(s);
      }
    }
  }
}

// ---------------- fallback GEMM with fp32 B (head only, if ws too small) ----------------
__global__ __launch_bounds__(256, 2) void gemm_f32b(const unsigned short* __restrict__ A,
                                                    const float* __restrict__ Bw,
                                                    float* __restrict__ Cout,
                                                    int M, int N, int K){
  __shared__ unsigned short As[128 * 32];
  __shared__ unsigned short Bs[128 * 32];
  const int tid = threadIdx.x;
  const int lane = tid & 63, wid = tid >> 6;
  const int l15 = lane & 15, g = lane >> 4;
  const int wr = wid >> 1, wc = wid & 1;
  const int m0 = blockIdx.x * 128, n0 = blockIdx.y * 128;
  const int bcol = tid & 127, bhalf = tid >> 7;
  f32x4 acc[4][4];
  #pragma unroll
  for (int m = 0; m < 4; ++m)
    #pragma unroll
    for (int n = 0; n < 4; ++n)
      #pragma unroll
      for (int i = 0; i < 4; ++i) acc[m][n][i] = 0.0f;
  for (int kk = 0; kk < K; kk += 32){
    __syncthreads();
    #pragma unroll
    for (int cc = 0; cc < 2; ++cc){
      int c = tid + cc * 256;
      int row = c >> 2, kc = (c & 3) << 3;
      uint4 d = *(const uint4*)(A + (size_t)(m0 + row) * K + kk + kc);
      *(uint4*)(&As[row * 32 + kc]) = d;
    }
    {
      const float* bp = Bw + (size_t)(kk + bhalf * 16) * N + n0 + bcol;
      float f[16];
      #pragma unroll
      for (int j = 0; j < 16; ++j) f[j] = bp[(size_t)j * N];
      unsigned int pk[8];
      #pragma unroll
      for (int j = 0; j < 8; ++j)
        pk[j] = (unsigned int)f2bf(f[2*j]) | ((unsigned int)f2bf(f[2*j+1]) << 16);
      int sw = (bcol >> 1) & 3;
      int c0 = ((bhalf << 1)     ) ^ sw;
      int c1 = ((bhalf << 1) | 1 ) ^ sw;
      uint4 w0; w0.x = pk[0]; w0.y = pk[1]; w0.z = pk[2]; w0.w = pk[3];
      uint4 w1; w1.x = pk[4]; w1.y = pk[5]; w1.z = pk[6]; w1.w = pk[7];
      *(uint4*)(&Bs[bcol * 32 + c0 * 8]) = w0;
      *(uint4*)(&Bs[bcol * 32 + c1 * 8]) = w1;
    }
    __syncthreads();
    short8 a[4], b[4];
    #pragma unroll
    for (int m = 0; m < 4; ++m)
      a[m] = *(const short8*)(&As[(wr*64 + m*16 + l15) * 32 + g*8]);
    #pragma unroll
    for (int n = 0; n < 4; ++n){
      int col = wc*64 + n*16 + l15;
      b[n] = *(const short8*)(&Bs[col * 32 + (g ^ ((col >> 1) & 3)) * 8]);
    }
    #pragma unroll
    for (int m = 0; m < 4; ++m)
      #pragma unroll
      for (int n = 0; n < 4; ++n)
        acc[m][n] = __builtin_amdgcn_mfma_f32_16x16x32_bf16(a[m], b[n], acc[m][n], 0, 0, 0);
  }
  #pragma unroll
  for (int m = 0; m < 4; ++m)
    #pragma unroll
    for (int n = 0; n < 4; ++n){
      int row0 = m0 + wr*64 + m*16 + g*4;
      int col  = n0 + wc*64 + n*16 + l15;
      #pragma unroll
      for (int i = 0; i < 4; ++i)
        Cout[(size_t)(row0 + i) * N + col] = acc[m][n][i];
    }
}

// ------- flash attention: 8 waves/block, 16 q-rows per wave, KV tile 64 ----------------
__global__ __launch_bounds__(512) void attn_kernel(const unsigned short* __restrict__ q,
                                                   const unsigned short* __restrict__ k,
                                                   const unsigned short* __restrict__ vt,
                                                   unsigned short* __restrict__ ctx){
  const int tid = threadIdx.x;
  const int lane = tid & 63, w = tid >> 6;      // w in [0,8)
  const int l15 = lane & 15, g = lane >> 4;
  const int bx = (int)gridDim.x - 1 - (int)blockIdx.x;  // heavy blocks first
  const int q0 = bx * 128 + w * 16;             // this wave's 16 q rows
  const int hh = blockIdx.y;
  const int tb = blockIdx.z * SEQ;

  __shared__ unsigned short Ks[64][72];    // [kv][d]
  __shared__ unsigned short Vs[64][72];    // [d][t]
  __shared__ unsigned short Ps[8][16][72]; // per-wave P round-trip

  short8 qa[2];
  #pragma unroll
  for (int kd = 0; kd < 2; ++kd)
    qa[kd] = *(const short8*)(q + (size_t)(tb + q0 + l15) * HID + hh*HD + kd*32 + g*8);

  float m_run[4], l_run[4];
  f32x4 o_acc[4];
  #pragma unroll
  for (int i = 0; i < 4; ++i){ m_run[i] = -1e30f; l_run[i] = 0.0f; }
  #pragma unroll
  for (int dt = 0; dt < 4; ++dt)
    #pragma unroll
    for (int i = 0; i < 4; ++i) o_acc[dt][i] = 0.0f;

  const int ntile = 2 * bx + 2;
  const int srow = tid >> 3, sc = (tid & 7) * 8;   // 512 threads: one uint4 each
  const unsigned short* kbase = k  + (size_t)(tb + srow) * HID + hh*HD + sc;
  const unsigned short* vbase = vt + (size_t)(hh*HD + srow) * T_TOK + tb + sc;

  for (int kt = 0; kt < ntile; ++kt){
    const int kv0 = kt * 64;
    __syncthreads();
    *(uint4*)(&Ks[srow][sc]) = *(const uint4*)(kbase + (size_t)kv0 * HID);
    *(uint4*)(&Vs[srow][sc]) = *(const uint4*)(vbase + kv0);
    __syncthreads();
    const int dq = q0 + 15 - kv0;
    const int nct = (dq < 0) ? 0 : min(4, (dq >> 4) + 1);
    if (nct <= 0) continue;                 // barrier counts stay uniform

    float pv[4][4];
    #pragma unroll
    for (int ct = 0; ct < 4; ++ct){
      if (ct < nct){
        f32x4 scv;
        #pragma unroll
        for (int i = 0; i < 4; ++i) scv[i] = 0.0f;
        scv = __builtin_amdgcn_mfma_f32_16x16x32_bf16(qa[0],
                *(const short8*)(&Ks[ct*16 + l15][g*8]), scv, 0, 0, 0);
        scv = __builtin_amdgcn_mfma_f32_16x16x32_bf16(qa[1],
                *(const short8*)(&Ks[ct*16 + l15][32 + g*8]), scv, 0, 0, 0);
        #pragma unroll
        for (int i = 0; i < 4; ++i){
          float s = fminf(fmaxf(scv[i], -1000.0f), 1000.0f);
          int row = q0 + g*4 + i;
          int col = kv0 + ct*16 + l15;
          pv[ct][i] = (col > row) ? -1e30f : s;
        }
      } else {
        #pragma unroll
        for (int i = 0; i < 4; ++i) pv[ct][i] = -1e30f;
      }
    }
    #pragma unroll
    for (int i = 0; i < 4; ++i){
      float mx = fmaxf(fmaxf(pv[0][i], pv[1][i]), fmaxf(pv[2][i], pv[3][i]));
      #pragma unroll
      for (int msk = 1; msk < 16; msk <<= 1) mx = fmaxf(mx, __shfl_xor(mx, msk));
      if (!__all(mx <= m_run[i] + 8.0f)){         // T13 defer-max
        float mnew = fmaxf(m_run[i], mx);
        float scale = __expf(m_run[i] - mnew);
        m_run[i] = mnew;
        l_run[i] *= scale;
        #pragma unroll
        for (int dt = 0; dt < 4; ++dt) o_acc[dt][i] *= scale;
      }
      float psum = 0.0f;
      #pragma unroll
      for (int ct = 0; ct < 4; ++ct){
        if (ct < nct){
          float p = __expf(pv[ct][i] - m_run[i]);
          pv[ct][i] = p; psum += p;
        } else pv[ct][i] = 0.0f;
      }
      #pragma unroll
      for (int msk = 1; msk < 16; msk <<= 1) psum += __shfl_xor(psum, msk);
      l_run[i] += psum;
    }
    #pragma unroll
    for (int ct = 0; ct < 4; ++ct)          // write all 4 (zeros beyond nct)
      #pragma unroll
      for (int i = 0; i < 4; ++i)
        Ps[w][g*4 + i][ct*16 + l15] = f2bf(pv[ct][i]);
    const int nks = (nct + 1) >> 1;
    #pragma unroll
    for (int ks = 0; ks < 2; ++ks){
      if (ks < nks){
        short8 ap = *(const short8*)(&Ps[w][l15][ks*32 + g*8]);
        #pragma unroll
        for (int dt = 0; dt < 4; ++dt){
          short8 vb = *(const short8*)(&Vs[dt*16 + l15][ks*32 + g*8]);
          o_acc[dt] = __builtin_amdgcn_mfma_f32_16x16x32_bf16(ap, vb, o_acc[dt], 0, 0, 0);
        }
      }
    }
  }
  #pragma unroll
  for (int i = 0; i < 4; ++i) l_run[i] = 1.0f / l_run[i];   // one rcp per row
  #pragma unroll
  for (int dt = 0; dt < 4; ++dt)
    #pragma unroll
    for (int i = 0; i < 4; ++i){
      float o = o_acc[dt][i] * l_run[i];
      ctx[(size_t)(tb + q0 + g*4 + i) * HID + hh*HD + dt*16 + l15] = f2bf(o);
    }
}

extern "C" void kernel_launch(void* const* d_in, const int* in_sizes, int n_in,
                              void* d_out, int out_size, void* d_ws, size_t ws_size,
                              hipStream_t stream){
  const int*   ids    = (const int*)d_in[0];
  const float* embedW = (const float*)d_in[1];
  const float* Wq = (const float*)d_in[2];
  const float* Wk = (const float*)d_in[3];
  const float* Wv = (const float*)d_in[4];
  const float* Wo = (const float*)d_in[5];
  const float* Wg = (const float*)d_in[6];
  const float* Wu = (const float*)d_in[7];
  const float* Wd = (const float*)d_in[8];
  const float* n1 = (const float*)d_in[9];
  const float* n2 = (const float*)d_in[10];
  const float* nf = (const float*)d_in[11];
  const float* Wh = (const float*)d_in[12];
  float* out = (float*)d_out;

  // d_out scratch (dead until head GEMM, which reads only ws-resident xn/WhT)
  char* scb = (char*)d_out;
  unsigned short* qb  = (unsigned short*)(scb + 0);
  unsigned short* kb  = (unsigned short*)(scb + 8388608);
  unsigned short* vtb = (unsigned short*)(scb + 16777216);   // V^T [HID][T]
  unsigned short* ctx = (unsigned short*)(scb + 25165824);
  unsigned short* gb  = (unsigned short*)(scb + 33554432);
  float* cosT = (float*)(scb + 100663296);
  float* sinT = (float*)(scb + 100925440);
  float* h_fallback   = (float*)(scb + 104857600);
  unsigned short* WtQ = (unsigned short*)(scb + 134217728);  // 16 MB (Q,K,V,O contiguous)
  unsigned short* WtK = (unsigned short*)(scb + 150994944);
  unsigned short* WtV = (unsigned short*)(scb + 167772160);
  unsigned short* WtO = (unsigned short*)(scb + 184549376);
  unsigned short* WtG = (unsigned short*)(scb + 201326592);  // 64 MB
  unsigned short* WtU = (unsigned short*)(scb + 268435456);  // 64 MB
  unsigned short* WtD = (unsigned short*)(scb + 335544320);  // 64 MB -> ends 384 MB

  unsigned short* xn = (unsigned short*)d_ws;                // 8 MB
  float* h = (ws_size >= 25165824u) ? (float*)((char*)d_ws + 8388608) : h_fallback;
  unsigned short* WhT = (ws_size >= 90701824u)
                      ? (unsigned short*)((char*)d_ws + 25165824) : nullptr;

  // weight converts: QKVO in one launch; G/U/D per-weight; head linear
  convert_w_qkvo<<<dim3(16, 16, 32), 256, 0, stream>>>(Wq, Wk, Wv, Wo, WtQ);
  convert_w_swz<<<dim3(64, 16, 8), 256, 0, stream>>>(Wg, WtG, HID, INTER);
  convert_w_swz<<<dim3(64, 16, 8), 256, 0, stream>>>(Wu, WtU, HID, INTER);
  convert_w_swz<<<dim3(16, 64, 8), 256, 0, stream>>>(Wd, WtD, INTER, HID);
  if (WhT)
    convert_w_lin<<<dim3(500, 16, 1), 256, 0, stream>>>(Wh, WhT, HID, VOCAB);

  embed_kernel<<<4096, 256, 0, stream>>>(ids, embedW, h);
  rope_tab_kernel<<<256, 256, 0, stream>>>(cosT, sinT);

  for (int l = 0; l < NLAYER; ++l){
    rmsnorm_kernel<<<4096, 256, 0, stream>>>(h, n1 + l*HID, xn, nullptr);
    gemm_qkv<<<dim3(32, 24), 256, 0, stream>>>(xn, WtQ + (size_t)l*HID*HID,
                                               WtK + (size_t)l*HID*HID,
                                               WtV + (size_t)l*HID*HID, qb, kb, vtb,
                                               cosT, sinT);
    attn_kernel<<<dim3(16, 16, 2), 512, 0, stream>>>(qb, kb, vtb, ctx);
    gemm_od<<<dim3(64, 8), 256, 0, stream>>>(ctx, WtO + (size_t)l*HID*HID,
                                             h, h, HID, HID);
    rmsnorm_kernel<<<4096, 256, 0, stream>>>(h, n2 + l*HID, xn, nullptr);
    gemm_gusilu<<<dim3(32, 32), 256, 0, stream>>>(xn, WtG + (size_t)l*HID*INTER,
                                                  WtU + (size_t)l*HID*INTER, gb);
    gemm_od<<<dim3(64, 8), 256, 0, stream>>>(gb, WtD + (size_t)l*HID*INTER,
                                             h, h, INTER, HID);
  }

  rmsnorm_kernel<<<4096, 256, 0, stream>>>(h, nf, xn, out + 131072000);
  if (WhT)
    gemm_head8p<<<dim3(16, 125), 512, 0, stream>>>(xn, WhT, out);
  else
    gemm_f32b<<<dim3(32, 250), 256, 0, stream>>>(xn, Wh, out, T_TOK, VOCAB, HID);
}

// Round 15
// 3558.033 us; speedup vs baseline: 1.1602x; 1.0243x over previous
//
#include <hip/hip_runtime.h>

#define T_TOK 4096
#define SEQ   2048
#define HID   1024
#define NH    16
#define HD    64
#define INTER 4096
#define NLAYER 8
#define VOCAB 32000

typedef short short8 __attribute__((ext_vector_type(8)));
typedef float f32x4  __attribute__((ext_vector_type(4)));

__device__ __forceinline__ unsigned short f2bf(float f){
  unsigned int u = __builtin_bit_cast(unsigned int, f);
  u += 0x7fffu + ((u >> 16) & 1u);
  return (unsigned short)(u >> 16);
}
__device__ __forceinline__ float bf2f(unsigned short b){
  unsigned int u = ((unsigned int)b) << 16;
  return __builtin_bit_cast(float, u);
}

#define GLOAD_LDS16(gsrc, ldst) \
  __builtin_amdgcn_global_load_lds((const __attribute__((address_space(1))) void*)(gsrc), \
                                   (__attribute__((address_space(3))) void*)(ldst), 16, 0, 0)

// ---------------- embedding gather ----------------
__global__ __launch_bounds__(256) void embed_kernel(const int* __restrict__ ids,
                                                    const float* __restrict__ W,
                                                    float* __restrict__ h){
  int i = blockIdx.x * 256 + threadIdx.x;   // float4 index over [T][256]
  int t = i >> 8, c = i & 255;
  ((float4*)h)[i] = ((const float4*)(W + (size_t)ids[t] * HID))[c];
}

// ---------------- rope tables ----------------
__global__ __launch_bounds__(256) void rope_tab_kernel(float* __restrict__ cosT,
                                                       float* __restrict__ sinT){
  int i = blockIdx.x * 256 + threadIdx.x;   // s*32 + f
  int s = i >> 5, f = i & 31;
  float inv = expf(-((2.0f * (float)f) / 64.0f) * logf(100000.0f));
  float ang = (float)s * inv;
  cosT[i] = cosf(ang);
  sinT[i] = sinf(ang);
}

// ---------------- rmsnorm (fp32 in -> bf16 out, optional fp32 normed copy) ----------------
__global__ __launch_bounds__(256) void rmsnorm_kernel(const float* __restrict__ h,
                                                      const float* __restrict__ w,
                                                      unsigned short* __restrict__ out,
                                                      float* hcopy){
  int t = blockIdx.x, tid = threadIdx.x;
  float4 v = ((const float4*)(h + (size_t)t * HID))[tid];
  float ss = v.x*v.x + v.y*v.y + v.z*v.z + v.w*v.w;
  #pragma unroll
  for (int m = 1; m < 64; m <<= 1) ss += __shfl_xor(ss, m);
  __shared__ float red[4];
  if ((tid & 63) == 0) red[tid >> 6] = ss;
  __syncthreads();
  float r = rsqrtf((red[0] + red[1] + red[2] + red[3]) * (1.0f / HID) + 1e-5f);
  float4 wv = ((const float4*)w)[tid];
  float nx = v.x * r * wv.x;
  float ny = v.y * r * wv.y;
  float nz = v.z * r * wv.z;
  float nw = v.w * r * wv.w;
  ushort4 o;
  o.x = f2bf(nx); o.y = f2bf(ny); o.z = f2bf(nz); o.w = f2bf(nw);
  ((ushort4*)(out + (size_t)t * HID))[tid] = o;
  if (hcopy){
    float4 hv; hv.x = nx; hv.y = ny; hv.z = nz; hv.w = nw;
    ((float4*)(hcopy + (size_t)t * HID))[tid] = hv;
  }
}

// ------- convert (QKVO, all layers): fp32 [K][N] -> bf16 W^T [N][K], chunk-XOR swizzled --
__global__ __launch_bounds__(256) void convert_w_qkvo(const float* __restrict__ W0,
                                                      const float* __restrict__ W1,
                                                      const float* __restrict__ W2,
                                                      const float* __restrict__ W3,
                                                      unsigned short* __restrict__ Wt){
  __shared__ unsigned short t_lds[64][72];
  const int z = blockIdx.z, sel = z >> 3, l = z & 7;
  const float* W = ((sel == 0) ? W0 : (sel == 1) ? W1 : (sel == 2) ? W2 : W3)
                 + (size_t)l * HID * HID;
  unsigned short* dst = Wt + (size_t)z * HID * HID;
  const int n0 = blockIdx.x * 64, k0 = blockIdx.y * 64;
  const int tid = threadIdx.x;
  const int tr = tid >> 4, tc = tid & 15;
  #pragma unroll
  for (int i = 0; i < 4; ++i){
    int kk = tr + i * 16;
    float4 v = *(const float4*)(W + (size_t)(k0 + kk) * HID + n0 + tc * 4);
    t_lds[tc*4+0][kk] = f2bf(v.x);
    t_lds[tc*4+1][kk] = f2bf(v.y);
    t_lds[tc*4+2][kk] = f2bf(v.z);
    t_lds[tc*4+3][kk] = f2bf(v.w);
  }
  __syncthreads();
  const int n = tid >> 2, cp = tid & 3;
  #pragma unroll
  for (int j = 0; j < 2; ++j){
    int c = cp * 2 + j;
    uint4 d = *(const uint4*)(&t_lds[n][c * 8]);
    *(uint4*)(dst + (size_t)(n0 + n) * HID + k0 + ((c ^ (n & 7)) << 3)) = d;
  }
}

// ------- convert (layer weights): fp32 [K][N] -> bf16 W^T [N][K], chunk-XOR swizzled ----
__global__ __launch_bounds__(256) void convert_w_swz(const float* __restrict__ W,
                                                     unsigned short* __restrict__ Wt,
                                                     int K, int N){
  __shared__ unsigned short t_lds[64][72];
  W  += (size_t)blockIdx.z * K * N;
  Wt += (size_t)blockIdx.z * K * N;
  const int n0 = blockIdx.x * 64, k0 = blockIdx.y * 64;
  const int tid = threadIdx.x;
  const int tr = tid >> 4, tc = tid & 15;
  #pragma unroll
  for (int i = 0; i < 4; ++i){
    int kk = tr + i * 16;
    float4 v = *(const float4*)(W + (size_t)(k0 + kk) * N + n0 + tc * 4);
    t_lds[tc*4+0][kk] = f2bf(v.x);
    t_lds[tc*4+1][kk] = f2bf(v.y);
    t_lds[tc*4+2][kk] = f2bf(v.z);
    t_lds[tc*4+3][kk] = f2bf(v.w);
  }
  __syncthreads();
  const int n = tid >> 2, cp = tid & 3;
  #pragma unroll
  for (int j = 0; j < 2; ++j){
    int c = cp * 2 + j;
    uint4 d = *(const uint4*)(&t_lds[n][c * 8]);
    *(uint4*)(Wt + (size_t)(n0 + n) * K + k0 + ((c ^ (n & 7)) << 3)) = d;
  }
}

// ------- convert (head weight): fp32 [K][N] -> bf16 W^T [N][K] linear ----------------
__global__ __launch_bounds__(256) void convert_w_lin(const float* __restrict__ W,
                                                     unsigned short* __restrict__ Wt,
                                                     int K, int N){
  __shared__ unsigned short t_lds[64][72];
  const int n0 = blockIdx.x * 64, k0 = blockIdx.y * 64;
  const int tid = threadIdx.x;
  const int tr = tid >> 4, tc = tid & 15;
  #pragma unroll
  for (int i = 0; i < 4; ++i){
    int kk = tr + i * 16;
    float4 v = *(const float4*)(W + (size_t)(k0 + kk) * N + n0 + tc * 4);
    t_lds[tc*4+0][kk] = f2bf(v.x);
    t_lds[tc*4+1][kk] = f2bf(v.y);
    t_lds[tc*4+2][kk] = f2bf(v.z);
    t_lds[tc*4+3][kk] = f2bf(v.w);
  }
  __syncthreads();
  const int n = tid >> 2, cp = tid & 3;
  #pragma unroll
  for (int j = 0; j < 2; ++j){
    int c = cp * 2 + j;
    uint4 d = *(const uint4*)(&t_lds[n][c * 8]);
    *(uint4*)(Wt + (size_t)(n0 + n) * K + k0 + c * 8) = d;
  }
}

// ===== core A (layer GEMMs): 128x128 tile, BK=64, pre-swizzled B, swizzled A src =====
__device__ __forceinline__ void gemm_core64(const unsigned short* __restrict__ A,
                                            const unsigned short* __restrict__ Bt,
                                            int K, int m0, int n0,
                                            unsigned short* As, unsigned short* Bs,
                                            f32x4 (&acc)[4][4]){
  const int tid = threadIdx.x;
  const int lane = tid & 63, w = tid >> 6;
  const int l15 = lane & 15, g = lane >> 4;
  const int lr = lane >> 3;
  const int lc = lane & 7;
  const int wr = w >> 1, wc = w & 1;
  const int axor = ((lc ^ lr) << 3);

  #pragma unroll
  for (int m = 0; m < 4; ++m)
    #pragma unroll
    for (int n = 0; n < 4; ++n)
      #pragma unroll
      for (int i = 0; i < 4; ++i) acc[m][n][i] = 0.0f;

  for (int kk = 0; kk < K; kk += 64){
    __syncthreads();
    #pragma unroll
    for (int i = 0; i < 4; ++i){
      int rb = (i * 4 + w) * 8;
      GLOAD_LDS16(A  + (size_t)(m0 + rb + lr) * K + kk + axor,      As + rb * 64);
      GLOAD_LDS16(Bt + (size_t)(n0 + rb + lr) * K + kk + (lc << 3), Bs + rb * 64);
    }
    __syncthreads();
    short8 a[4][2], b[4][2];
    const int x = l15 & 7;
    #pragma unroll
    for (int m = 0; m < 4; ++m){
      int row = wr * 64 + m * 16 + l15;
      a[m][0] = *(const short8*)(As + row * 64 + ((g       ^ x) << 3));
      a[m][1] = *(const short8*)(As + row * 64 + (((4 + g) ^ x) << 3));
    }
    #pragma unroll
    for (int n = 0; n < 4; ++n){
      int row = wc * 64 + n * 16 + l15;
      b[n][0] = *(const short8*)(Bs + row * 64 + ((g       ^ x) << 3));
      b[n][1] = *(const short8*)(Bs + row * 64 + (((4 + g) ^ x) << 3));
    }
    #pragma unroll
    for (int m = 0; m < 4; ++m)
      #pragma unroll
      for (int n = 0; n < 4; ++n){
        acc[m][n] = __builtin_amdgcn_mfma_f32_16x16x32_bf16(a[m][0], b[n][0], acc[m][n], 0, 0, 0);
        acc[m][n] = __builtin_amdgcn_mfma_f32_16x16x32_bf16(a[m][1], b[n][1], acc[m][n], 0, 0, 0);
      }
  }
}

// MODE 0: bf16 out. MODE 1: f32 resid+acc. MODE 2: bf16 C^T. MODE 3: f32 nontemporal.
template<int MODE>
__device__ __forceinline__ void gemm_epi(const f32x4 (&acc)[4][4], void* Cout,
                                         const float* __restrict__ resid,
                                         int N, int m0, int n0, int ldt){
  const int tid = threadIdx.x;
  const int lane = tid & 63, w = tid >> 6;
  const int l15 = lane & 15, g = lane >> 4;
  const int wr = w >> 1, wc = w & 1;
  #pragma unroll
  for (int m = 0; m < 4; ++m){
    #pragma unroll
    for (int n = 0; n < 4; ++n){
      int row0 = m0 + wr * 64 + m * 16 + g * 4;
      int col  = n0 + wc * 64 + n * 16 + l15;
      #pragma unroll
      for (int i = 0; i < 4; ++i){
        float v = acc[m][n][i];
        if (MODE == 0){
          ((unsigned short*)Cout)[(size_t)(row0 + i) * N + col] = f2bf(v);
        } else if (MODE == 1){
          size_t idx = (size_t)(row0 + i) * N + col;
          ((float*)Cout)[idx] = resid[idx] + v;
        } else if (MODE == 2){
          ((unsigned short*)Cout)[(size_t)col * ldt + (row0 + i)] = f2bf(v);
        } else {
          __builtin_nontemporal_store(v, &((float*)Cout)[(size_t)(row0 + i) * N + col]);
        }
      }
    }
  }
}

// ===== O/D GEMM: 64x128 tile, BK=64, 4 waves, 2 blocks/CU at grid 512 =====
__global__ __launch_bounds__(256) void gemm_od(const unsigned short* __restrict__ A,
                                               const unsigned short* __restrict__ Bt,
                                               float* __restrict__ Cout,
                                               const float* __restrict__ resid,
                                               int K, int N){
  __shared__ unsigned short As[64 * 64];
  __shared__ unsigned short Bs[128 * 64];
  const int tid = threadIdx.x;
  const int lane = tid & 63, w = tid >> 6;
  const int l15 = lane & 15, g = lane >> 4;
  const int lr = lane >> 3, lc = lane & 7;
  const int axor = ((lc ^ lr) << 3);
  const int m0 = blockIdx.x * 64, n0 = blockIdx.y * 128;

  f32x4 acc[4][2];
  #pragma unroll
  for (int m = 0; m < 4; ++m)
    #pragma unroll
    for (int n = 0; n < 2; ++n)
      #pragma unroll
      for (int i = 0; i < 4; ++i) acc[m][n][i] = 0.0f;

  for (int kk = 0; kk < K; kk += 64){
    __syncthreads();
    #pragma unroll
    for (int i = 0; i < 2; ++i){
      int rb = (i * 4 + w) * 8;
      GLOAD_LDS16(A + (size_t)(m0 + rb + lr) * K + kk + axor, As + rb * 64);
    }
    #pragma unroll
    for (int i = 0; i < 4; ++i){
      int rb = (i * 4 + w) * 8;
      GLOAD_LDS16(Bt + (size_t)(n0 + rb + lr) * K + kk + (lc << 3), Bs + rb * 64);
    }
    __syncthreads();
    short8 a[4][2], b[2][2];
    const int x = l15 & 7;
    #pragma unroll
    for (int m = 0; m < 4; ++m){
      int row = m * 16 + l15;
      a[m][0] = *(const short8*)(As + row * 64 + ((g       ^ x) << 3));
      a[m][1] = *(const short8*)(As + row * 64 + (((4 + g) ^ x) << 3));
    }
    #pragma unroll
    for (int n = 0; n < 2; ++n){
      int row = w * 32 + n * 16 + l15;
      b[n][0] = *(const short8*)(Bs + row * 64 + ((g       ^ x) << 3));
      b[n][1] = *(const short8*)(Bs + row * 64 + (((4 + g) ^ x) << 3));
    }
    #pragma unroll
    for (int m = 0; m < 4; ++m)
      #pragma unroll
      for (int n = 0; n < 2; ++n){
        acc[m][n] = __builtin_amdgcn_mfma_f32_16x16x32_bf16(a[m][0], b[n][0], acc[m][n], 0, 0, 0);
        acc[m][n] = __builtin_amdgcn_mfma_f32_16x16x32_bf16(a[m][1], b[n][1], acc[m][n], 0, 0, 0);
      }
  }
  #pragma unroll
  for (int m = 0; m < 4; ++m)
    #pragma unroll
    for (int n = 0; n < 2; ++n){
      int row0 = m0 + m * 16 + g * 4;
      int col  = n0 + w * 32 + n * 16 + l15;
      #pragma unroll
      for (int i = 0; i < 4; ++i){
        size_t idx = (size_t)(row0 + i) * N + col;
        Cout[idx] = resid[idx] + acc[m][n][i];
      }
    }
}

// ===== head GEMM: 256x256 tile, 8 waves, 4-phase/K-tile counted-vmcnt pipeline =====
#define WAITV4 asm volatile("s_waitcnt vmcnt(4)" ::: "memory")
#define WAITV2 asm volatile("s_waitcnt vmcnt(2)" ::: "memory")
#define WAITV0 asm volatile("s_waitcnt vmcnt(0)" ::: "memory")
#define HBAR() { __builtin_amdgcn_s_barrier(); asm volatile("" ::: "memory"); }

__global__ __launch_bounds__(512, 2) void gemm_head8p(const unsigned short* __restrict__ A,
                                                      const unsigned short* __restrict__ Bt,
                                                      float* __restrict__ out){
  __shared__ unsigned short smem8[65536];   // 128 KB: [buf][mat][half][128][64]
  const int tid = threadIdx.x;
  const int lane = tid & 63, w = tid >> 6;        // 8 waves
  const int l15 = lane & 15, g = lane >> 4;
  const int wr = w >> 2, wc = w & 3;              // 2 (M) x 4 (N)
  const int lr8 = lane >> 3, lc = lane & 7;
  const int axor = ((lc ^ lr8) << 3);             // source chunk pre-swizzle
  const int x = l15 & 7;
  const int sl0 = ((g ^ x) << 3), sl1 = (((4 + g) ^ x) << 3);  // read slots (row&7 == x)
  const int m0 = blockIdx.x * 256, n0 = blockIdx.y * 256;
  const int K = HID, nt = HID / 64;               // 16 K-tiles

  f32x4 acc[8][4];
  #pragma unroll
  for (int m = 0; m < 8; ++m)
    #pragma unroll
    for (int n = 0; n < 4; ++n)
      #pragma unroll
      for (int i = 0; i < 4; ++i) acc[m][n][i] = 0.0f;

  #define STAGE_HALF(BUF, MAT, HALF, KK)                                           \
  {                                                                                \
    unsigned short* dbase = smem8 + ((((BUF)*2+(MAT))*2+(HALF)) << 13) + (w*8)*64; \
    const unsigned short* G = (MAT) ? Bt : A;                                      \
    const int brc = (MAT) ? n0 : m0;                                               \
    int r0 = w*8 + lr8, r1 = r0 + 64;                                              \
    int g0, g1;                                                                    \
    if (MAT){ g0 = brc + ((r0>>5)<<6) + ((HALF)<<5) + (r0&31);                     \
              g1 = brc + ((r1>>5)<<6) + ((HALF)<<5) + (r1&31); }                   \
    else    { g0 = brc + ((r0>>6)<<7) + ((HALF)<<6) + (r0&63);                     \
              g1 = brc + ((r1>>6)<<7) + ((HALF)<<6) + (r1&63); }                   \
    GLOAD_LDS16(G + (size_t)g0*K + (KK) + axor, dbase);                            \
    GLOAD_LDS16(G + (size_t)g1*K + (KK) + axor, dbase + 64*64);                    \
  }

  STAGE_HALF(0, 0, 0, 0)
  STAGE_HALF(0, 1, 0, 0)
  STAGE_HALF(0, 1, 1, 0)
  STAGE_HALF(0, 0, 1, 0)
  WAITV4;
  HBAR();

  for (int t = 0; t < nt; ++t){
    const int buf = t & 1, sb = buf ^ 1;
    const int kkn = (t + 1) * 64;
    const bool st = (t + 1 < nt);
    const int aB0 = ((buf*2+0)*2+0) << 13;
    const int aB1 = aB0 + 8192;
    const int bB0 = ((buf*2+1)*2+0) << 13;
    const int bB1 = bB0 + 8192;
    short8 a[4][2], b0[2][2], b1[2][2];

    // ---- phase 0: A0 x B0 ----
    #pragma unroll
    for (int m4 = 0; m4 < 4; ++m4){
      const unsigned short* p = smem8 + aB0 + (wr*64 + m4*16 + l15) * 64;
      a[m4][0] = *(const short8*)(p + sl0);
      a[m4][1] = *(const short8*)(p + sl1);
    }
    #pragma unroll
    for (int n2 = 0; n2 < 2; ++n2){
      const unsigned short* p = smem8 + bB0 + (wc*32 + n2*16 + l15) * 64;
      b0[n2][0] = *(const short8*)(p + sl0);
      b0[n2][1] = *(const short8*)(p + sl1);
    }
    if (st){ STAGE_HALF(sb, 0, 0, kkn) }
    HBAR();
    __builtin_amdgcn_s_setprio(1);
    #pragma unroll
    for (int m4 = 0; m4 < 4; ++m4)
      #pragma unroll
      for (int n2 = 0; n2 < 2; ++n2){
        acc[m4][n2] = __builtin_amdgcn_mfma_f32_16x16x32_bf16(a[m4][0], b0[n2][0], acc[m4][n2], 0, 0, 0);
        acc[m4][n2] = __builtin_amdgcn_mfma_f32_16x16x32_bf16(a[m4][1], b0[n2][1], acc[m4][n2], 0, 0, 0);
      }
    __builtin_amdgcn_s_setprio(0);
    if (st){ WAITV4; } else { WAITV2; }
    HBAR();

    // ---- phase 1: A0 x B1 ----
    #pragma unroll
    for (int n2 = 0; n2 < 2; ++n2){
      const unsigned short* p = smem8 + bB1 + (wc*32 + n2*16 + l15) * 64;
      b1[n2][0] = *(const short8*)(p + sl0);
      b1[n2][1] = *(const short8*)(p + sl1);
    }
    if (st){ STAGE_HALF(sb, 1, 0, kkn) }
    HBAR();
    __builtin_amdgcn_s_setprio(1);
    #pragma unroll
    for (int m4 = 0; m4 < 4; ++m4)
      #pragma unroll
      for (int n2 = 0; n2 < 2; ++n2){
        acc[m4][2+n2] = __builtin_amdgcn_mfma_f32_16x16x32_bf16(a[m4][0], b1[n2][0], acc[m4][2+n2], 0, 0, 0);
        acc[m4][2+n2] = __builtin_amdgcn_mfma_f32_16x16x32_bf16(a[m4][1], b1[n2][1], acc[m4][2+n2], 0, 0, 0);
      }
    __builtin_amdgcn_s_setprio(0);
    if (st){ WAITV4; } else { WAITV0; }
    HBAR();

    // ---- phase 2: A1 x B0 ----
    #pragma unroll
    for (int m4 = 0; m4 < 4; ++m4){
      const unsigned short* p = smem8 + aB1 + (wr*64 + m4*16 + l15) * 64;
      a[m4][0] = *(const short8*)(p + sl0);
      a[m4][1] = *(const short8*)(p + sl1);
    }
    if (st){ STAGE_HALF(sb, 1, 1, kkn) }
    HBAR();
    __builtin_amdgcn_s_setprio(1);
    #pragma unroll
    for (int m4 = 0; m4 < 4; ++m4)
      #pragma unroll
      for (int n2 = 0; n2 < 2; ++n2){
        acc[4+m4][n2] = __builtin_amdgcn_mfma_f32_16x16x32_bf16(a[m4][0], b0[n2][0], acc[4+m4][n2], 0, 0, 0);
        acc[4+m4][n2] = __builtin_amdgcn_mfma_f32_16x16x32_bf16(a[m4][1], b0[n2][1], acc[4+m4][n2], 0, 0, 0);
      }
    __builtin_amdgcn_s_setprio(0);
    HBAR();

    // ---- phase 3: A1 x B1 ----
    if (st){ STAGE_HALF(sb, 0, 1, kkn) }
    HBAR();
    __builtin_amdgcn_s_setprio(1);
    #pragma unroll
    for (int m4 = 0; m4 < 4; ++m4)
      #pragma unroll
      for (int n2 = 0; n2 < 2; ++n2){
        acc[4+m4][2+n2] = __builtin_amdgcn_mfma_f32_16x16x32_bf16(a[m4][0], b1[n2][0], acc[4+m4][2+n2], 0, 0, 0);
        acc[4+m4][2+n2] = __builtin_amdgcn_mfma_f32_16x16x32_bf16(a[m4][1], b1[n2][1], acc[4+m4][2+n2], 0, 0, 0);
      }
    __builtin_amdgcn_s_setprio(0);
    if (st){ WAITV4; }
    HBAR();
  }
  #undef STAGE_HALF

  #pragma unroll
  for (int m = 0; m < 8; ++m)
    #pragma unroll
    for (int n = 0; n < 4; ++n){
      int row0 = m0 + wr*128 + m*16 + g*4;
      int col  = n0 + wc*64  + n*16 + l15;
      #pragma unroll
      for (int i = 0; i < 4; ++i)
        __builtin_nontemporal_store(acc[m][n][i], &out[(size_t)(row0 + i) * VOCAB + col]);
    }
}

// fused QKV + RoPE epilogue: grid.y = 24 (8 q | 8 k | 8 v-transposed-via-LDS)
__global__ __launch_bounds__(256) void gemm_qkv(const unsigned short* __restrict__ A,
                                                const unsigned short* __restrict__ BtQ,
                                                const unsigned short* __restrict__ BtK,
                                                const unsigned short* __restrict__ BtV,
                                                unsigned short* qb, unsigned short* kb,
                                                unsigned short* vt,
                                                const float* __restrict__ cosT,
                                                const float* __restrict__ sinT){
  __shared__ unsigned short smem[128 * 64 * 2];   // As | Bs; reused for V transpose
  unsigned short* As = smem;
  unsigned short* Bs = smem + 128 * 64;
  const int nb = blockIdx.y, sel = nb >> 3, n0 = (nb & 7) * 128;
  const unsigned short* Bt = (sel == 0) ? BtQ : (sel == 1) ? BtK : BtV;
  const int m0 = blockIdx.x * 128;
  f32x4 acc[4][4];
  gemm_core64(A, Bt, HID, m0, n0, As, Bs, acc);
  const int tid = threadIdx.x;
  const int lane = tid & 63, w = tid >> 6;
  const int l15 = lane & 15, g = lane >> 4;
  const int wr = w >> 1, wc = w & 1;
  if (sel == 2){
    // V^T via LDS transpose: coalesced uint4 rows instead of 8B-stride-8KB scatter
    unsigned short (*T)[136] = (unsigned short(*)[136])smem;  // [64 cols][128+pad tokens]
    #pragma unroll
    for (int p = 0; p < 2; ++p){
      __syncthreads();                       // LDS free / prev pass consumed
      if (wc == p){
        #pragma unroll
        for (int m = 0; m < 4; ++m)
          #pragma unroll
          for (int n = 0; n < 4; ++n)
            #pragma unroll
            for (int k2 = 0; k2 < 2; ++k2){
              unsigned int pk = (unsigned int)f2bf(acc[m][n][2*k2])
                              | ((unsigned int)f2bf(acc[m][n][2*k2+1]) << 16);
              *(unsigned int*)(&T[n*16 + l15][wr*64 + m*16 + g*4 + 2*k2]) = pk;
            }
      }
      __syncthreads();
      #pragma unroll
      for (int j = 0; j < 4; ++j){
        int idx = tid + j * 256;             // 64 cols x 16 chunks
        int colL = idx >> 4, ch = idx & 15;
        *(uint4*)(vt + (size_t)(n0 + p*64 + colL) * T_TOK + m0 + ch*8) =
            *(const uint4*)(&T[colL][ch*8]);
      }
    }
    return;
  }
  // RoPE epilogue for Q/K: fragment pair (n, n+2) = rotate-half pair (f, f+32)
  unsigned short* outp = sel ? kb : qb;
  const float qs = sel ? 1.0f : 0.125f;
  #pragma unroll
  for (int m = 0; m < 4; ++m){
    #pragma unroll
    for (int n = 0; n < 2; ++n){
      int row0 = m0 + wr * 64 + m * 16 + g * 4;
      int col  = n0 + wc * 64 + n * 16 + l15;
      int f    = (col & 63);
      #pragma unroll
      for (int i = 0; i < 4; ++i){
        int t = row0 + i, s = t & (SEQ - 1);
        float c  = cosT[s * 32 + f];
        float sn = sinT[s * 32 + f];
        float x0 = acc[m][n][i], x1 = acc[m][n + 2][i];
        outp[(size_t)t * HID + col]      = f2bf((x0 * c - x1 * sn) * qs);
        outp[(size_t)t * HID + col + 32] = f2bf((x1 * c + x0 * sn) * qs);
      }
    }
  }
}

// fused gate+up+silu: each block computes both G and U tiles, writes silu(g)*u
__global__ __launch_bounds__(256) void gemm_gusilu(const unsigned short* __restrict__ A,
                                                   const unsigned short* __restrict__ BtG,
                                                   const unsigned short* __restrict__ BtU,
                                                   unsigned short* __restrict__ gb){
  __shared__ unsigned short As[128 * 64];
  __shared__ unsigned short Bs[128 * 64];
  const int m0 = blockIdx.x * 128, n0 = blockIdx.y * 128;
  f32x4 acc[4][4];
  gemm_core64(A, BtG, HID, m0, n0, As, Bs, acc);
  unsigned int gp[4][4][2];
  #pragma unroll
  for (int m = 0; m < 4; ++m)
    #pragma unroll
    for (int n = 0; n < 4; ++n){
      gp[m][n][0] = (unsigned int)f2bf(acc[m][n][0]) | ((unsigned int)f2bf(acc[m][n][1]) << 16);
      gp[m][n][1] = (unsigned int)f2bf(acc[m][n][2]) | ((unsigned int)f2bf(acc[m][n][3]) << 16);
    }
  gemm_core64(A, BtU, HID, m0, n0, As, Bs, acc);
  const int tid = threadIdx.x;
  const int lane = tid & 63, w = tid >> 6;
  const int l15 = lane & 15, g = lane >> 4;
  const int wr = w >> 1, wc = w & 1;
  #pragma unroll
  for (int m = 0; m < 4; ++m){
    #pragma unroll
    for (int n = 0; n < 4; ++n){
      int row0 = m0 + wr * 64 + m * 16 + g * 4;
      int col  = n0 + wc * 64 + n * 16 + l15;
      #pragma unroll
      for (int i = 0; i < 4; ++i){
        float gv = bf2f((unsigned short)(gp[m][n][i >> 1] >> ((i & 1) * 16)));
        float u  = acc[m][n][i];
        float s  = (gv / (1.0f + __expf(-gv))) * u;
        gb[(size_t)(row0 + i) * INTER + col] = f2bf(s);
      }
    }
  }
}

// ---------------- fallback GEMM with fp32 B (head only, if ws too small) ----------------
__global__ __launch_bounds__(256, 2) void gemm_f32b(const unsigned short* __restrict__ A,
                                                    const float* __restrict__ Bw,
                                                    float* __restrict__ Cout,
                                                    int M, int N, int K){
  __shared__ unsigned short As[128 * 32];
  __shared__ unsigned short Bs[128 * 32];
  const int tid = threadIdx.x;
  const int lane = tid & 63, wid = tid >> 6;
  const int l15 = lane & 15, g = lane >> 4;
  const int wr = wid >> 1, wc = wid & 1;
  const int m0 = blockIdx.x * 128, n0 = blockIdx.y * 128;
  const int bcol = tid & 127, bhalf = tid >> 7;
  f32x4 acc[4][4];
  #pragma unroll
  for (int m = 0; m < 4; ++m)
    #pragma unroll
    for (int n = 0; n < 4; ++n)
      #pragma unroll
      for (int i = 0; i < 4; ++i) acc[m][n][i] = 0.0f;
  for (int kk = 0; kk < K; kk += 32){
    __syncthreads();
    #pragma unroll
    for (int cc = 0; cc < 2; ++cc){
      int c = tid + cc * 256;
      int row = c >> 2, kc = (c & 3) << 3;
      uint4 d = *(const uint4*)(A + (size_t)(m0 + row) * K + kk + kc);
      *(uint4*)(&As[row * 32 + kc]) = d;
    }
    {
      const float* bp = Bw + (size_t)(kk + bhalf * 16) * N + n0 + bcol;
      float f[16];
      #pragma unroll
      for (int j = 0; j < 16; ++j) f[j] = bp[(size_t)j * N];
      unsigned int pk[8];
      #pragma unroll
      for (int j = 0; j < 8; ++j)
        pk[j] = (unsigned int)f2bf(f[2*j]) | ((unsigned int)f2bf(f[2*j+1]) << 16);
      int sw = (bcol >> 1) & 3;
      int c0 = ((bhalf << 1)     ) ^ sw;
      int c1 = ((bhalf << 1) | 1 ) ^ sw;
      uint4 w0; w0.x = pk[0]; w0.y = pk[1]; w0.z = pk[2]; w0.w = pk[3];
      uint4 w1; w1.x = pk[4]; w1.y = pk[5]; w1.z = pk[6]; w1.w = pk[7];
      *(uint4*)(&Bs[bcol * 32 + c0 * 8]) = w0;
      *(uint4*)(&Bs[bcol * 32 + c1 * 8]) = w1;
    }
    __syncthreads();
    short8 a[4], b[4];
    #pragma unroll
    for (int m = 0; m < 4; ++m)
      a[m] = *(const short8*)(&As[(wr*64 + m*16 + l15) * 32 + g*8]);
    #pragma unroll
    for (int n = 0; n < 4; ++n){
      int col = wc*64 + n*16 + l15;
      b[n] = *(const short8*)(&Bs[col * 32 + (g ^ ((col >> 1) & 3)) * 8]);
    }
    #pragma unroll
    for (int m = 0; m < 4; ++m)
      #pragma unroll
      for (int n = 0; n < 4; ++n)
        acc[m][n] = __builtin_amdgcn_mfma_f32_16x16x32_bf16(a[m], b[n], acc[m][n], 0, 0, 0);
  }
  #pragma unroll
  for (int m = 0; m < 4; ++m)
    #pragma unroll
    for (int n = 0; n < 4; ++n){
      int row0 = m0 + wr*64 + m*16 + g*4;
      int col  = n0 + wc*64 + n*16 + l15;
      #pragma unroll
      for (int i = 0; i < 4; ++i)
        Cout[(size_t)(row0 + i) * N + col] = acc[m][n][i];
    }
}

// ------- flash attention: 8 waves/block, 16 q-rows per wave, KV tile 64, T14 prefetch ---
__global__ __launch_bounds__(512) void attn_kernel(const unsigned short* __restrict__ q,
                                                   const unsigned short* __restrict__ k,
                                                   const unsigned short* __restrict__ vt,
                                                   unsigned short* __restrict__ ctx){
  const int tid = threadIdx.x;
  const int lane = tid & 63, w = tid >> 6;      // w in [0,8)
  const int l15 = lane & 15, g = lane >> 4;
  const int bx = (int)gridDim.x - 1 - (int)blockIdx.x;  // heavy blocks first
  const int q0 = bx * 128 + w * 16;             // this wave's 16 q rows
  const int hh = blockIdx.y;
  const int tb = blockIdx.z * SEQ;

  __shared__ unsigned short Ks[64][72];    // [kv][d]
  __shared__ unsigned short Vs[64][72];    // [d][t]
  __shared__ unsigned short Ps[8][16][72]; // per-wave P round-trip

  short8 qa[2];
  #pragma unroll
  for (int kd = 0; kd < 2; ++kd)
    qa[kd] = *(const short8*)(q + (size_t)(tb + q0 + l15) * HID + hh*HD + kd*32 + g*8);

  float m_run[4], l_run[4];
  f32x4 o_acc[4];
  #pragma unroll
  for (int i = 0; i < 4; ++i){ m_run[i] = -1e30f; l_run[i] = 0.0f; }
  #pragma unroll
  for (int dt = 0; dt < 4; ++dt)
    #pragma unroll
    for (int i = 0; i < 4; ++i) o_acc[dt][i] = 0.0f;

  const int ntile = 2 * bx + 2;
  const int srow = tid >> 3, sc = (tid & 7) * 8;   // 512 threads: one uint4 each
  const unsigned short* kbase = k  + (size_t)(tb + srow) * HID + hh*HD + sc;
  const unsigned short* vbase = vt + (size_t)(hh*HD + srow) * T_TOK + tb + sc;

  uint4 kreg = *(const uint4*)(kbase);     // tile 0 preload
  uint4 vreg = *(const uint4*)(vbase);

  for (int kt = 0; kt < ntile; ++kt){
    const int kv0 = kt * 64;
    __syncthreads();                       // prev tile's compute done (LDS free)
    *(uint4*)(&Ks[srow][sc]) = kreg;
    *(uint4*)(&Vs[srow][sc]) = vreg;
    __syncthreads();                       // tile visible to all waves
    if (kt + 1 < ntile){                   // T14: issue next-tile loads before compute
      kreg = *(const uint4*)(kbase + (size_t)(kv0 + 64) * HID);
      vreg = *(const uint4*)(vbase + kv0 + 64);
    }
    const int dq = q0 + 15 - kv0;
    const int nct = (dq < 0) ? 0 : min(4, (dq >> 4) + 1);
    if (nct <= 0) continue;                 // barrier counts stay uniform

    float pv[4][4];
    #pragma unroll
    for (int ct = 0; ct < 4; ++ct){
      if (ct < nct){
        f32x4 scv;
        #pragma unroll
        for (int i = 0; i < 4; ++i) scv[i] = 0.0f;
        scv = __builtin_amdgcn_mfma_f32_16x16x32_bf16(qa[0],
                *(const short8*)(&Ks[ct*16 + l15][g*8]), scv, 0, 0, 0);
        scv = __builtin_amdgcn_mfma_f32_16x16x32_bf16(qa[1],
                *(const short8*)(&Ks[ct*16 + l15][32 + g*8]), scv, 0, 0, 0);
        #pragma unroll
        for (int i = 0; i < 4; ++i){
          float s = fminf(fmaxf(scv[i], -1000.0f), 1000.0f);
          int row = q0 + g*4 + i;
          int col = kv0 + ct*16 + l15;
          pv[ct][i] = (col > row) ? -1e30f : s;
        }
      } else {
        #pragma unroll
        for (int i = 0; i < 4; ++i) pv[ct][i] = -1e30f;
      }
    }
    #pragma unroll
    for (int i = 0; i < 4; ++i){
      float mx = fmaxf(fmaxf(pv[0][i], pv[1][i]), fmaxf(pv[2][i], pv[3][i]));
      #pragma unroll
      for (int msk = 1; msk < 16; msk <<= 1) mx = fmaxf(mx, __shfl_xor(mx, msk));
      if (!__all(mx <= m_run[i] + 8.0f)){         // T13 defer-max
        float mnew = fmaxf(m_run[i], mx);
        float scale = __expf(m_run[i] - mnew);
        m_run[i] = mnew;
        l_run[i] *= scale;
        #pragma unroll
        for (int dt = 0; dt < 4; ++dt) o_acc[dt][i] *= scale;
      }
      float psum = 0.0f;
      #pragma unroll
      for (int ct = 0; ct < 4; ++ct){
        if (ct < nct){
          float p = __expf(pv[ct][i] - m_run[i]);
          pv[ct][i] = p; psum += p;
        } else pv[ct][i] = 0.0f;
      }
      #pragma unroll
      for (int msk = 1; msk < 16; msk <<= 1) psum += __shfl_xor(psum, msk);
      l_run[i] += psum;
    }
    #pragma unroll
    for (int ct = 0; ct < 4; ++ct)          // write all 4 (zeros beyond nct)
      #pragma unroll
      for (int i = 0; i < 4; ++i)
        Ps[w][g*4 + i][ct*16 + l15] = f2bf(pv[ct][i]);
    const int nks = (nct + 1) >> 1;
    #pragma unroll
    for (int ks = 0; ks < 2; ++ks){
      if (ks < nks){
        short8 ap = *(const short8*)(&Ps[w][l15][ks*32 + g*8]);
        #pragma unroll
        for (int dt = 0; dt < 4; ++dt){
          short8 vb = *(const short8*)(&Vs[dt*16 + l15][ks*32 + g*8]);
          o_acc[dt] = __builtin_amdgcn_mfma_f32_16x16x32_bf16(ap, vb, o_acc[dt], 0, 0, 0);
        }
      }
    }
  }
  #pragma unroll
  for (int i = 0; i < 4; ++i) l_run[i] = 1.0f / l_run[i];   // one rcp per row
  #pragma unroll
  for (int dt = 0; dt < 4; ++dt)
    #pragma unroll
    for (int i = 0; i < 4; ++i){
      float o = o_acc[dt][i] * l_run[i];
      ctx[(size_t)(tb + q0 + g*4 + i) * HID + hh*HD + dt*16 + l15] = f2bf(o);
    }
}

extern "C" void kernel_launch(void* const* d_in, const int* in_sizes, int n_in,
                              void* d_out, int out_size, void* d_ws, size_t ws_size,
                              hipStream_t stream){
  const int*   ids    = (const int*)d_in[0];
  const float* embedW = (const float*)d_in[1];
  const float* Wq = (const float*)d_in[2];
  const float* Wk = (const float*)d_in[3];
  const float* Wv = (const float*)d_in[4];
  const float* Wo = (const float*)d_in[5];
  const float* Wg = (const float*)d_in[6];
  const float* Wu = (const float*)d_in[7];
  const float* Wd = (const float*)d_in[8];
  const float* n1 = (const float*)d_in[9];
  const float* n2 = (const float*)d_in[10];
  const float* nf = (const float*)d_in[11];
  const float* Wh = (const float*)d_in[12];
  float* out = (float*)d_out;

  // d_out scratch (dead until head GEMM, which reads only ws-resident xn/WhT)
  char* scb = (char*)d_out;
  unsigned short* qb  = (unsigned short*)(scb + 0);
  unsigned short* kb  = (unsigned short*)(scb + 8388608);
  unsigned short* vtb = (unsigned short*)(scb + 16777216);   // V^T [HID][T]
  unsigned short* ctx = (unsigned short*)(scb + 25165824);
  unsigned short* gb  = (unsigned short*)(scb + 33554432);
  float* cosT = (float*)(scb + 100663296);
  float* sinT = (float*)(scb + 100925440);
  float* h_fallback   = (float*)(scb + 104857600);
  unsigned short* WtQ = (unsigned short*)(scb + 134217728);  // 16 MB (Q,K,V,O contiguous)
  unsigned short* WtK = (unsigned short*)(scb + 150994944);
  unsigned short* WtV = (unsigned short*)(scb + 167772160);
  unsigned short* WtO = (unsigned short*)(scb + 184549376);
  unsigned short* WtG = (unsigned short*)(scb + 201326592);  // 64 MB
  unsigned short* WtU = (unsigned short*)(scb + 268435456);  // 64 MB
  unsigned short* WtD = (unsigned short*)(scb + 335544320);  // 64 MB -> ends 384 MB

  unsigned short* xn = (unsigned short*)d_ws;                // 8 MB
  float* h = (ws_size >= 25165824u) ? (float*)((char*)d_ws + 8388608) : h_fallback;
  unsigned short* WhT = (ws_size >= 90701824u)
                      ? (unsigned short*)((char*)d_ws + 25165824) : nullptr;

  // weight converts: QKVO in one launch; G/U/D per-weight; head linear
  convert_w_qkvo<<<dim3(16, 16, 32), 256, 0, stream>>>(Wq, Wk, Wv, Wo, WtQ);
  convert_w_swz<<<dim3(64, 16, 8), 256, 0, stream>>>(Wg, WtG, HID, INTER);
  convert_w_swz<<<dim3(64, 16, 8), 256, 0, stream>>>(Wu, WtU, HID, INTER);
  convert_w_swz<<<dim3(16, 64, 8), 256, 0, stream>>>(Wd, WtD, INTER, HID);
  if (WhT)
    convert_w_lin<<<dim3(500, 16, 1), 256, 0, stream>>>(Wh, WhT, HID, VOCAB);

  embed_kernel<<<4096, 256, 0, stream>>>(ids, embedW, h);
  rope_tab_kernel<<<256, 256, 0, stream>>>(cosT, sinT);

  for (int l = 0; l < NLAYER; ++l){
    rmsnorm_kernel<<<4096, 256, 0, stream>>>(h, n1 + l*HID, xn, nullptr);
    gemm_qkv<<<dim3(32, 24), 256, 0, stream>>>(xn, WtQ + (size_t)l*HID*HID,
                                               WtK + (size_t)l*HID*HID,
                                               WtV + (size_t)l*HID*HID, qb, kb, vtb,
                                               cosT, sinT);
    attn_kernel<<<dim3(16, 16, 2), 512, 0, stream>>>(qb, kb, vtb, ctx);
    gemm_od<<<dim3(64, 8), 256, 0, stream>>>(ctx, WtO + (size_t)l*HID*HID,
                                             h, h, HID, HID);
    rmsnorm_kernel<<<4096, 256, 0, stream>>>(h, n2 + l*HID, xn, nullptr);
    gemm_gusilu<<<dim3(32, 32), 256, 0, stream>>>(xn, WtG + (size_t)l*HID*INTER,
                                                  WtU + (size_t)l*HID*INTER, gb);
    gemm_od<<<dim3(64, 8), 256, 0, stream>>>(gb, WtD + (size_t)l*HID*INTER,
                                             h, h, INTER, HID);
  }

  rmsnorm_kernel<<<4096, 256, 0, stream>>>(h, nf, xn, out + 131072000);
  if (WhT)
    gemm_head8p<<<dim3(16, 125), 512, 0, stream>>>(xn, WhT, out);
  else
    gemm_f32b<<<dim3(32, 250), 256, 0, stream>>>(xn, Wh, out, T_TOK, VOCAB, HID);
}

// Round 16
// 3555.669 us; speedup vs baseline: 1.1610x; 1.0007x over previous
//
#include <hip/hip_runtime.h>

#define T_TOK 4096
#define SEQ   2048
#define HID   1024
#define NH    16
#define HD    64
#define INTER 4096
#define NLAYER 8
#define VOCAB 32000

typedef short short8 __attribute__((ext_vector_type(8)));
typedef float f32x4  __attribute__((ext_vector_type(4)));

__device__ __forceinline__ unsigned short f2bf(float f){
  unsigned int u = __builtin_bit_cast(unsigned int, f);
  u += 0x7fffu + ((u >> 16) & 1u);
  return (unsigned short)(u >> 16);
}
__device__ __forceinline__ float bf2f(unsigned short b){
  unsigned int u = ((unsigned int)b) << 16;
  return __builtin_bit_cast(float, u);
}

#define GLOAD_LDS16(gsrc, ldst) \
  __builtin_amdgcn_global_load_lds((const __attribute__((address_space(1))) void*)(gsrc), \
                                   (__attribute__((address_space(3))) void*)(ldst), 16, 0, 0)

// ---------------- embedding gather ----------------
__global__ __launch_bounds__(256) void embed_kernel(const int* __restrict__ ids,
                                                    const float* __restrict__ W,
                                                    float* __restrict__ h){
  int i = blockIdx.x * 256 + threadIdx.x;   // float4 index over [T][256]
  int t = i >> 8, c = i & 255;
  ((float4*)h)[i] = ((const float4*)(W + (size_t)ids[t] * HID))[c];
}

// ---------------- rope tables ----------------
__global__ __launch_bounds__(256) void rope_tab_kernel(float* __restrict__ cosT,
                                                       float* __restrict__ sinT){
  int i = blockIdx.x * 256 + threadIdx.x;   // s*32 + f
  int s = i >> 5, f = i & 31;
  float inv = expf(-((2.0f * (float)f) / 64.0f) * logf(100000.0f));
  float ang = (float)s * inv;
  cosT[i] = cosf(ang);
  sinT[i] = sinf(ang);
}

// ---------------- rmsnorm (fp32 in -> bf16 out, optional fp32 normed copy) ----------------
__global__ __launch_bounds__(256) void rmsnorm_kernel(const float* __restrict__ h,
                                                      const float* __restrict__ w,
                                                      unsigned short* __restrict__ out,
                                                      float* hcopy){
  int t = blockIdx.x, tid = threadIdx.x;
  float4 v = ((const float4*)(h + (size_t)t * HID))[tid];
  float ss = v.x*v.x + v.y*v.y + v.z*v.z + v.w*v.w;
  #pragma unroll
  for (int m = 1; m < 64; m <<= 1) ss += __shfl_xor(ss, m);
  __shared__ float red[4];
  if ((tid & 63) == 0) red[tid >> 6] = ss;
  __syncthreads();
  float r = rsqrtf((red[0] + red[1] + red[2] + red[3]) * (1.0f / HID) + 1e-5f);
  float4 wv = ((const float4*)w)[tid];
  float nx = v.x * r * wv.x;
  float ny = v.y * r * wv.y;
  float nz = v.z * r * wv.z;
  float nw = v.w * r * wv.w;
  ushort4 o;
  o.x = f2bf(nx); o.y = f2bf(ny); o.z = f2bf(nz); o.w = f2bf(nw);
  ((ushort4*)(out + (size_t)t * HID))[tid] = o;
  if (hcopy){
    float4 hv; hv.x = nx; hv.y = ny; hv.z = nz; hv.w = nw;
    ((float4*)(hcopy + (size_t)t * HID))[tid] = hv;
  }
}

// ------- convert (QKVO, all layers): fp32 [K][N] -> bf16 W^T [N][K], chunk-XOR swizzled --
__global__ __launch_bounds__(256) void convert_w_qkvo(const float* __restrict__ W0,
                                                      const float* __restrict__ W1,
                                                      const float* __restrict__ W2,
                                                      const float* __restrict__ W3,
                                                      unsigned short* __restrict__ Wt){
  __shared__ unsigned short t_lds[64][72];
  const int z = blockIdx.z, sel = z >> 3, l = z & 7;
  const float* W = ((sel == 0) ? W0 : (sel == 1) ? W1 : (sel == 2) ? W2 : W3)
                 + (size_t)l * HID * HID;
  unsigned short* dst = Wt + (size_t)z * HID * HID;
  const int n0 = blockIdx.x * 64, k0 = blockIdx.y * 64;
  const int tid = threadIdx.x;
  const int tr = tid >> 4, tc = tid & 15;
  #pragma unroll
  for (int i = 0; i < 4; ++i){
    int kk = tr + i * 16;
    float4 v = *(const float4*)(W + (size_t)(k0 + kk) * HID + n0 + tc * 4);
    t_lds[tc*4+0][kk] = f2bf(v.x);
    t_lds[tc*4+1][kk] = f2bf(v.y);
    t_lds[tc*4+2][kk] = f2bf(v.z);
    t_lds[tc*4+3][kk] = f2bf(v.w);
  }
  __syncthreads();
  const int n = tid >> 2, cp = tid & 3;
  #pragma unroll
  for (int j = 0; j < 2; ++j){
    int c = cp * 2 + j;
    uint4 d = *(const uint4*)(&t_lds[n][c * 8]);
    *(uint4*)(dst + (size_t)(n0 + n) * HID + k0 + ((c ^ (n & 7)) << 3)) = d;
  }
}

// ------- convert (G+U, all layers, one launch): fp32 [HID][INTER] -> bf16 W^T swizzled --
__global__ __launch_bounds__(256) void convert_w_gu(const float* __restrict__ WG,
                                                    const float* __restrict__ WU,
                                                    unsigned short* __restrict__ WtG,
                                                    unsigned short* __restrict__ WtU){
  __shared__ unsigned short t_lds[64][72];
  const int z = blockIdx.z, sel = z >> 3, l = z & 7;
  const float* W = (sel ? WU : WG) + (size_t)l * HID * INTER;
  unsigned short* Wt = (sel ? WtU : WtG) + (size_t)l * HID * INTER;
  const int n0 = blockIdx.x * 64, k0 = blockIdx.y * 64;
  const int tid = threadIdx.x;
  const int tr = tid >> 4, tc = tid & 15;
  #pragma unroll
  for (int i = 0; i < 4; ++i){
    int kk = tr + i * 16;
    float4 v = *(const float4*)(W + (size_t)(k0 + kk) * INTER + n0 + tc * 4);
    t_lds[tc*4+0][kk] = f2bf(v.x);
    t_lds[tc*4+1][kk] = f2bf(v.y);
    t_lds[tc*4+2][kk] = f2bf(v.z);
    t_lds[tc*4+3][kk] = f2bf(v.w);
  }
  __syncthreads();
  const int n = tid >> 2, cp = tid & 3;
  #pragma unroll
  for (int j = 0; j < 2; ++j){
    int c = cp * 2 + j;
    uint4 d = *(const uint4*)(&t_lds[n][c * 8]);
    *(uint4*)(Wt + (size_t)(n0 + n) * HID + k0 + ((c ^ (n & 7)) << 3)) = d;
  }
}

// ------- convert (layer weights): fp32 [K][N] -> bf16 W^T [N][K], chunk-XOR swizzled ----
__global__ __launch_bounds__(256) void convert_w_swz(const float* __restrict__ W,
                                                     unsigned short* __restrict__ Wt,
                                                     int K, int N){
  __shared__ unsigned short t_lds[64][72];
  W  += (size_t)blockIdx.z * K * N;
  Wt += (size_t)blockIdx.z * K * N;
  const int n0 = blockIdx.x * 64, k0 = blockIdx.y * 64;
  const int tid = threadIdx.x;
  const int tr = tid >> 4, tc = tid & 15;
  #pragma unroll
  for (int i = 0; i < 4; ++i){
    int kk = tr + i * 16;
    float4 v = *(const float4*)(W + (size_t)(k0 + kk) * N + n0 + tc * 4);
    t_lds[tc*4+0][kk] = f2bf(v.x);
    t_lds[tc*4+1][kk] = f2bf(v.y);
    t_lds[tc*4+2][kk] = f2bf(v.z);
    t_lds[tc*4+3][kk] = f2bf(v.w);
  }
  __syncthreads();
  const int n = tid >> 2, cp = tid & 3;
  #pragma unroll
  for (int j = 0; j < 2; ++j){
    int c = cp * 2 + j;
    uint4 d = *(const uint4*)(&t_lds[n][c * 8]);
    *(uint4*)(Wt + (size_t)(n0 + n) * K + k0 + ((c ^ (n & 7)) << 3)) = d;
  }
}

// ------- convert (head weight): fp32 [K][N] -> bf16 W^T [N][K] linear ----------------
__global__ __launch_bounds__(256) void convert_w_lin(const float* __restrict__ W,
                                                     unsigned short* __restrict__ Wt,
                                                     int K, int N){
  __shared__ unsigned short t_lds[64][72];
  const int n0 = blockIdx.x * 64, k0 = blockIdx.y * 64;
  const int tid = threadIdx.x;
  const int tr = tid >> 4, tc = tid & 15;
  #pragma unroll
  for (int i = 0; i < 4; ++i){
    int kk = tr + i * 16;
    float4 v = *(const float4*)(W + (size_t)(k0 + kk) * N + n0 + tc * 4);
    t_lds[tc*4+0][kk] = f2bf(v.x);
    t_lds[tc*4+1][kk] = f2bf(v.y);
    t_lds[tc*4+2][kk] = f2bf(v.z);
    t_lds[tc*4+3][kk] = f2bf(v.w);
  }
  __syncthreads();
  const int n = tid >> 2, cp = tid & 3;
  #pragma unroll
  for (int j = 0; j < 2; ++j){
    int c = cp * 2 + j;
    uint4 d = *(const uint4*)(&t_lds[n][c * 8]);
    *(uint4*)(Wt + (size_t)(n0 + n) * K + k0 + c * 8) = d;
  }
}

// ===== core A (layer GEMMs): 128x128 tile, BK=64, pre-swizzled B, swizzled A src =====
__device__ __forceinline__ void gemm_core64(const unsigned short* __restrict__ A,
                                            const unsigned short* __restrict__ Bt,
                                            int K, int m0, int n0,
                                            unsigned short* As, unsigned short* Bs,
                                            f32x4 (&acc)[4][4]){
  const int tid = threadIdx.x;
  const int lane = tid & 63, w = tid >> 6;
  const int l15 = lane & 15, g = lane >> 4;
  const int lr = lane >> 3;
  const int lc = lane & 7;
  const int wr = w >> 1, wc = w & 1;
  const int axor = ((lc ^ lr) << 3);

  #pragma unroll
  for (int m = 0; m < 4; ++m)
    #pragma unroll
    for (int n = 0; n < 4; ++n)
      #pragma unroll
      for (int i = 0; i < 4; ++i) acc[m][n][i] = 0.0f;

  for (int kk = 0; kk < K; kk += 64){
    __syncthreads();
    #pragma unroll
    for (int i = 0; i < 4; ++i){
      int rb = (i * 4 + w) * 8;
      GLOAD_LDS16(A  + (size_t)(m0 + rb + lr) * K + kk + axor,      As + rb * 64);
      GLOAD_LDS16(Bt + (size_t)(n0 + rb + lr) * K + kk + (lc << 3), Bs + rb * 64);
    }
    __syncthreads();
    short8 a[4][2], b[4][2];
    const int x = l15 & 7;
    #pragma unroll
    for (int m = 0; m < 4; ++m){
      int row = wr * 64 + m * 16 + l15;
      a[m][0] = *(const short8*)(As + row * 64 + ((g       ^ x) << 3));
      a[m][1] = *(const short8*)(As + row * 64 + (((4 + g) ^ x) << 3));
    }
    #pragma unroll
    for (int n = 0; n < 4; ++n){
      int row = wc * 64 + n * 16 + l15;
      b[n][0] = *(const short8*)(Bs + row * 64 + ((g       ^ x) << 3));
      b[n][1] = *(const short8*)(Bs + row * 64 + (((4 + g) ^ x) << 3));
    }
    #pragma unroll
    for (int m = 0; m < 4; ++m)
      #pragma unroll
      for (int n = 0; n < 4; ++n){
        acc[m][n] = __builtin_amdgcn_mfma_f32_16x16x32_bf16(a[m][0], b[n][0], acc[m][n], 0, 0, 0);
        acc[m][n] = __builtin_amdgcn_mfma_f32_16x16x32_bf16(a[m][1], b[n][1], acc[m][n], 0, 0, 0);
      }
  }
}

// MODE 0: bf16 out. MODE 1: f32 resid+acc. MODE 2: bf16 C^T. MODE 3: f32 nontemporal.
template<int MODE>
__device__ __forceinline__ void gemm_epi(const f32x4 (&acc)[4][4], void* Cout,
                                         const float* __restrict__ resid,
                                         int N, int m0, int n0, int ldt){
  const int tid = threadIdx.x;
  const int lane = tid & 63, w = tid >> 6;
  const int l15 = lane & 15, g = lane >> 4;
  const int wr = w >> 1, wc = w & 1;
  #pragma unroll
  for (int m = 0; m < 4; ++m){
    #pragma unroll
    for (int n = 0; n < 4; ++n){
      int row0 = m0 + wr * 64 + m * 16 + g * 4;
      int col  = n0 + wc * 64 + n * 16 + l15;
      #pragma unroll
      for (int i = 0; i < 4; ++i){
        float v = acc[m][n][i];
        if (MODE == 0){
          ((unsigned short*)Cout)[(size_t)(row0 + i) * N + col] = f2bf(v);
        } else if (MODE == 1){
          size_t idx = (size_t)(row0 + i) * N + col;
          ((float*)Cout)[idx] = resid[idx] + v;
        } else if (MODE == 2){
          ((unsigned short*)Cout)[(size_t)col * ldt + (row0 + i)] = f2bf(v);
        } else {
          __builtin_nontemporal_store(v, &((float*)Cout)[(size_t)(row0 + i) * N + col]);
        }
      }
    }
  }
}

// ===== O/D GEMM: 64x128 tile, BK=64, 4 waves, 2 blocks/CU at grid 512 =====
__global__ __launch_bounds__(256) void gemm_od(const unsigned short* __restrict__ A,
                                               const unsigned short* __restrict__ Bt,
                                               float* __restrict__ Cout,
                                               const float* __restrict__ resid,
                                               int K, int N){
  __shared__ unsigned short As[64 * 64];
  __shared__ unsigned short Bs[128 * 64];
  const int tid = threadIdx.x;
  const int lane = tid & 63, w = tid >> 6;
  const int l15 = lane & 15, g = lane >> 4;
  const int lr = lane >> 3, lc = lane & 7;
  const int axor = ((lc ^ lr) << 3);
  const int m0 = blockIdx.x * 64, n0 = blockIdx.y * 128;

  f32x4 acc[4][2];
  #pragma unroll
  for (int m = 0; m < 4; ++m)
    #pragma unroll
    for (int n = 0; n < 2; ++n)
      #pragma unroll
      for (int i = 0; i < 4; ++i) acc[m][n][i] = 0.0f;

  for (int kk = 0; kk < K; kk += 64){
    __syncthreads();
    #pragma unroll
    for (int i = 0; i < 2; ++i){
      int rb = (i * 4 + w) * 8;
      GLOAD_LDS16(A + (size_t)(m0 + rb + lr) * K + kk + axor, As + rb * 64);
    }
    #pragma unroll
    for (int i = 0; i < 4; ++i){
      int rb = (i * 4 + w) * 8;
      GLOAD_LDS16(Bt + (size_t)(n0 + rb + lr) * K + kk + (lc << 3), Bs + rb * 64);
    }
    __syncthreads();
    short8 a[4][2], b[2][2];
    const int x = l15 & 7;
    #pragma unroll
    for (int m = 0; m < 4; ++m){
      int row = m * 16 + l15;
      a[m][0] = *(const short8*)(As + row * 64 + ((g       ^ x) << 3));
      a[m][1] = *(const short8*)(As + row * 64 + (((4 + g) ^ x) << 3));
    }
    #pragma unroll
    for (int n = 0; n < 2; ++n){
      int row = w * 32 + n * 16 + l15;
      b[n][0] = *(const short8*)(Bs + row * 64 + ((g       ^ x) << 3));
      b[n][1] = *(const short8*)(Bs + row * 64 + (((4 + g) ^ x) << 3));
    }
    #pragma unroll
    for (int m = 0; m < 4; ++m)
      #pragma unroll
      for (int n = 0; n < 2; ++n){
        acc[m][n] = __builtin_amdgcn_mfma_f32_16x16x32_bf16(a[m][0], b[n][0], acc[m][n], 0, 0, 0);
        acc[m][n] = __builtin_amdgcn_mfma_f32_16x16x32_bf16(a[m][1], b[n][1], acc[m][n], 0, 0, 0);
      }
  }
  #pragma unroll
  for (int m = 0; m < 4; ++m)
    #pragma unroll
    for (int n = 0; n < 2; ++n){
      int row0 = m0 + m * 16 + g * 4;
      int col  = n0 + w * 32 + n * 16 + l15;
      #pragma unroll
      for (int i = 0; i < 4; ++i){
        size_t idx = (size_t)(row0 + i) * N + col;
        Cout[idx] = resid[idx] + acc[m][n][i];
      }
    }
}

// ===== head GEMM: 256x256 tile, 8 waves, 4-phase/K-tile counted-vmcnt pipeline =====
#define WAITV4 asm volatile("s_waitcnt vmcnt(4)" ::: "memory")
#define WAITV2 asm volatile("s_waitcnt vmcnt(2)" ::: "memory")
#define WAITV0 asm volatile("s_waitcnt vmcnt(0)" ::: "memory")
#define HBAR() { __builtin_amdgcn_s_barrier(); asm volatile("" ::: "memory"); }

__global__ __launch_bounds__(512, 2) void gemm_head8p(const unsigned short* __restrict__ A,
                                                      const unsigned short* __restrict__ Bt,
                                                      float* __restrict__ out){
  __shared__ unsigned short smem8[65536];   // 128 KB: [buf][mat][half][128][64]
  const int tid = threadIdx.x;
  const int lane = tid & 63, w = tid >> 6;        // 8 waves
  const int l15 = lane & 15, g = lane >> 4;
  const int wr = w >> 2, wc = w & 3;              // 2 (M) x 4 (N)
  const int lr8 = lane >> 3, lc = lane & 7;
  const int axor = ((lc ^ lr8) << 3);             // source chunk pre-swizzle
  const int x = l15 & 7;
  const int sl0 = ((g ^ x) << 3), sl1 = (((4 + g) ^ x) << 3);  // read slots (row&7 == x)
  const int m0 = blockIdx.x * 256, n0 = blockIdx.y * 256;
  const int K = HID, nt = HID / 64;               // 16 K-tiles

  f32x4 acc[8][4];
  #pragma unroll
  for (int m = 0; m < 8; ++m)
    #pragma unroll
    for (int n = 0; n < 4; ++n)
      #pragma unroll
      for (int i = 0; i < 4; ++i) acc[m][n][i] = 0.0f;

  #define STAGE_HALF(BUF, MAT, HALF, KK)                                           \
  {                                                                                \
    unsigned short* dbase = smem8 + ((((BUF)*2+(MAT))*2+(HALF)) << 13) + (w*8)*64; \
    const unsigned short* G = (MAT) ? Bt : A;                                      \
    const int brc = (MAT) ? n0 : m0;                                               \
    int r0 = w*8 + lr8, r1 = r0 + 64;                                              \
    int g0, g1;                                                                    \
    if (MAT){ g0 = brc + ((r0>>5)<<6) + ((HALF)<<5) + (r0&31);                     \
              g1 = brc + ((r1>>5)<<6) + ((HALF)<<5) + (r1&31); }                   \
    else    { g0 = brc + ((r0>>6)<<7) + ((HALF)<<6) + (r0&63);                     \
              g1 = brc + ((r1>>6)<<7) + ((HALF)<<6) + (r1&63); }                   \
    GLOAD_LDS16(G + (size_t)g0*K + (KK) + axor, dbase);                            \
    GLOAD_LDS16(G + (size_t)g1*K + (KK) + axor, dbase + 64*64);                    \
  }

  STAGE_HALF(0, 0, 0, 0)
  STAGE_HALF(0, 1, 0, 0)
  STAGE_HALF(0, 1, 1, 0)
  STAGE_HALF(0, 0, 1, 0)
  WAITV4;
  HBAR();

  for (int t = 0; t < nt; ++t){
    const int buf = t & 1, sb = buf ^ 1;
    const int kkn = (t + 1) * 64;
    const bool st = (t + 1 < nt);
    const int aB0 = ((buf*2+0)*2+0) << 13;
    const int aB1 = aB0 + 8192;
    const int bB0 = ((buf*2+1)*2+0) << 13;
    const int bB1 = bB0 + 8192;
    short8 a[4][2], b0[2][2], b1[2][2];

    // ---- phase 0: A0 x B0 ----
    #pragma unroll
    for (int m4 = 0; m4 < 4; ++m4){
      const unsigned short* p = smem8 + aB0 + (wr*64 + m4*16 + l15) * 64;
      a[m4][0] = *(const short8*)(p + sl0);
      a[m4][1] = *(const short8*)(p + sl1);
    }
    #pragma unroll
    for (int n2 = 0; n2 < 2; ++n2){
      const unsigned short* p = smem8 + bB0 + (wc*32 + n2*16 + l15) * 64;
      b0[n2][0] = *(const short8*)(p + sl0);
      b0[n2][1] = *(const short8*)(p + sl1);
    }
    if (st){ STAGE_HALF(sb, 0, 0, kkn) }
    HBAR();
    __builtin_amdgcn_s_setprio(1);
    #pragma unroll
    for (int m4 = 0; m4 < 4; ++m4)
      #pragma unroll
      for (int n2 = 0; n2 < 2; ++n2){
        acc[m4][n2] = __builtin_amdgcn_mfma_f32_16x16x32_bf16(a[m4][0], b0[n2][0], acc[m4][n2], 0, 0, 0);
        acc[m4][n2] = __builtin_amdgcn_mfma_f32_16x16x32_bf16(a[m4][1], b0[n2][1], acc[m4][n2], 0, 0, 0);
      }
    __builtin_amdgcn_s_setprio(0);
    if (st){ WAITV4; } else { WAITV2; }
    HBAR();

    // ---- phase 1: A0 x B1 ----
    #pragma unroll
    for (int n2 = 0; n2 < 2; ++n2){
      const unsigned short* p = smem8 + bB1 + (wc*32 + n2*16 + l15) * 64;
      b1[n2][0] = *(const short8*)(p + sl0);
      b1[n2][1] = *(const short8*)(p + sl1);
    }
    if (st){ STAGE_HALF(sb, 1, 0, kkn) }
    HBAR();
    __builtin_amdgcn_s_setprio(1);
    #pragma unroll
    for (int m4 = 0; m4 < 4; ++m4)
      #pragma unroll
      for (int n2 = 0; n2 < 2; ++n2){
        acc[m4][2+n2] = __builtin_amdgcn_mfma_f32_16x16x32_bf16(a[m4][0], b1[n2][0], acc[m4][2+n2], 0, 0, 0);
        acc[m4][2+n2] = __builtin_amdgcn_mfma_f32_16x16x32_bf16(a[m4][1], b1[n2][1], acc[m4][2+n2], 0, 0, 0);
      }
    __builtin_amdgcn_s_setprio(0);
    if (st){ WAITV4; } else { WAITV0; }
    HBAR();

    // ---- phase 2: A1 x B0 ----
    #pragma unroll
    for (int m4 = 0; m4 < 4; ++m4){
      const unsigned short* p = smem8 + aB1 + (wr*64 + m4*16 + l15) * 64;
      a[m4][0] = *(const short8*)(p + sl0);
      a[m4][1] = *(const short8*)(p + sl1);
    }
    if (st){ STAGE_HALF(sb, 1, 1, kkn) }
    HBAR();
    __builtin_amdgcn_s_setprio(1);
    #pragma unroll
    for (int m4 = 0; m4 < 4; ++m4)
      #pragma unroll
      for (int n2 = 0; n2 < 2; ++n2){
        acc[4+m4][n2] = __builtin_amdgcn_mfma_f32_16x16x32_bf16(a[m4][0], b0[n2][0], acc[4+m4][n2], 0, 0, 0);
        acc[4+m4][n2] = __builtin_amdgcn_mfma_f32_16x16x32_bf16(a[m4][1], b0[n2][1], acc[4+m4][n2], 0, 0, 0);
      }
    __builtin_amdgcn_s_setprio(0);
    HBAR();

    // ---- phase 3: A1 x B1 ----
    if (st){ STAGE_HALF(sb, 0, 1, kkn) }
    HBAR();
    __builtin_amdgcn_s_setprio(1);
    #pragma unroll
    for (int m4 = 0; m4 < 4; ++m4)
      #pragma unroll
      for (int n2 = 0; n2 < 2; ++n2){
        acc[4+m4][2+n2] = __builtin_amdgcn_mfma_f32_16x16x32_bf16(a[m4][0], b1[n2][0], acc[4+m4][2+n2], 0, 0, 0);
        acc[4+m4][2+n2] = __builtin_amdgcn_mfma_f32_16x16x32_bf16(a[m4][1], b1[n2][1], acc[4+m4][2+n2], 0, 0, 0);
      }
    __builtin_amdgcn_s_setprio(0);
    if (st){ WAITV4; }
    HBAR();
  }
  #undef STAGE_HALF

  #pragma unroll
  for (int m = 0; m < 8; ++m)
    #pragma unroll
    for (int n = 0; n < 4; ++n){
      int row0 = m0 + wr*128 + m*16 + g*4;
      int col  = n0 + wc*64  + n*16 + l15;
      #pragma unroll
      for (int i = 0; i < 4; ++i)
        __builtin_nontemporal_store(acc[m][n][i], &out[(size_t)(row0 + i) * VOCAB + col]);
    }
}

// fused QKV + RoPE epilogue: grid.y = 24 (8 q | 8 k | 8 v-transposed-via-LDS)
__global__ __launch_bounds__(256) void gemm_qkv(const unsigned short* __restrict__ A,
                                                const unsigned short* __restrict__ BtQ,
                                                const unsigned short* __restrict__ BtK,
                                                const unsigned short* __restrict__ BtV,
                                                unsigned short* qb, unsigned short* kb,
                                                unsigned short* vt,
                                                const float* __restrict__ cosT,
                                                const float* __restrict__ sinT){
  __shared__ unsigned short smem[128 * 64 * 2];   // As | Bs; reused for V transpose
  unsigned short* As = smem;
  unsigned short* Bs = smem + 128 * 64;
  const int nb = blockIdx.y, sel = nb >> 3, n0 = (nb & 7) * 128;
  const unsigned short* Bt = (sel == 0) ? BtQ : (sel == 1) ? BtK : BtV;
  const int m0 = blockIdx.x * 128;
  f32x4 acc[4][4];
  gemm_core64(A, Bt, HID, m0, n0, As, Bs, acc);
  const int tid = threadIdx.x;
  const int lane = tid & 63, w = tid >> 6;
  const int l15 = lane & 15, g = lane >> 4;
  const int wr = w >> 1, wc = w & 1;
  if (sel == 2){
    // V^T via LDS transpose: coalesced uint4 rows instead of 8B-stride-8KB scatter
    unsigned short (*T)[136] = (unsigned short(*)[136])smem;  // [64 cols][128+pad tokens]
    #pragma unroll
    for (int p = 0; p < 2; ++p){
      __syncthreads();                       // LDS free / prev pass consumed
      if (wc == p){
        #pragma unroll
        for (int m = 0; m < 4; ++m)
          #pragma unroll
          for (int n = 0; n < 4; ++n)
            #pragma unroll
            for (int k2 = 0; k2 < 2; ++k2){
              unsigned int pk = (unsigned int)f2bf(acc[m][n][2*k2])
                              | ((unsigned int)f2bf(acc[m][n][2*k2+1]) << 16);
              *(unsigned int*)(&T[n*16 + l15][wr*64 + m*16 + g*4 + 2*k2]) = pk;
            }
      }
      __syncthreads();
      #pragma unroll
      for (int j = 0; j < 4; ++j){
        int idx = tid + j * 256;             // 64 cols x 16 chunks
        int colL = idx >> 4, ch = idx & 15;
        *(uint4*)(vt + (size_t)(n0 + p*64 + colL) * T_TOK + m0 + ch*8) =
            *(const uint4*)(&T[colL][ch*8]);
      }
    }
    return;
  }
  // RoPE epilogue for Q/K: fragment pair (n, n+2) = rotate-half pair (f, f+32)
  unsigned short* outp = sel ? kb : qb;
  const float qs = sel ? 1.0f : 0.125f;
  #pragma unroll
  for (int m = 0; m < 4; ++m){
    #pragma unroll
    for (int n = 0; n < 2; ++n){
      int row0 = m0 + wr * 64 + m * 16 + g * 4;
      int col  = n0 + wc * 64 + n * 16 + l15;
      int f    = (col & 63);
      #pragma unroll
      for (int i = 0; i < 4; ++i){
        int t = row0 + i, s = t & (SEQ - 1);
        float c  = cosT[s * 32 + f];
        float sn = sinT[s * 32 + f];
        float x0 = acc[m][n][i], x1 = acc[m][n + 2][i];
        outp[(size_t)t * HID + col]      = f2bf((x0 * c - x1 * sn) * qs);
        outp[(size_t)t * HID + col + 32] = f2bf((x1 * c + x0 * sn) * qs);
      }
    }
  }
}

// fused gate+up+silu: each block computes both G and U tiles, writes silu(g)*u
__global__ __launch_bounds__(256) void gemm_gusilu(const unsigned short* __restrict__ A,
                                                   const unsigned short* __restrict__ BtG,
                                                   const unsigned short* __restrict__ BtU,
                                                   unsigned short* __restrict__ gb){
  __shared__ unsigned short As[128 * 64];
  __shared__ unsigned short Bs[128 * 64];
  const int m0 = blockIdx.x * 128, n0 = blockIdx.y * 128;
  f32x4 acc[4][4];
  gemm_core64(A, BtG, HID, m0, n0, As, Bs, acc);
  unsigned int gp[4][4][2];
  #pragma unroll
  for (int m = 0; m < 4; ++m)
    #pragma unroll
    for (int n = 0; n < 4; ++n){
      gp[m][n][0] = (unsigned int)f2bf(acc[m][n][0]) | ((unsigned int)f2bf(acc[m][n][1]) << 16);
      gp[m][n][1] = (unsigned int)f2bf(acc[m][n][2]) | ((unsigned int)f2bf(acc[m][n][3]) << 16);
    }
  gemm_core64(A, BtU, HID, m0, n0, As, Bs, acc);
  const int tid = threadIdx.x;
  const int lane = tid & 63, w = tid >> 6;
  const int l15 = lane & 15, g = lane >> 4;
  const int wr = w >> 1, wc = w & 1;
  #pragma unroll
  for (int m = 0; m < 4; ++m){
    #pragma unroll
    for (int n = 0; n < 4; ++n){
      int row0 = m0 + wr * 64 + m * 16 + g * 4;
      int col  = n0 + wc * 64 + n * 16 + l15;
      #pragma unroll
      for (int i = 0; i < 4; ++i){
        float gv = bf2f((unsigned short)(gp[m][n][i >> 1] >> ((i & 1) * 16)));
        float u  = acc[m][n][i];
        float s  = (gv / (1.0f + __expf(-gv))) * u;
        gb[(size_t)(row0 + i) * INTER + col] = f2bf(s);
      }
    }
  }
}

// ---------------- fallback GEMM with fp32 B (head only, if ws too small) ----------------
__global__ __launch_bounds__(256, 2) void gemm_f32b(const unsigned short* __restrict__ A,
                                                    const float* __restrict__ Bw,
                                                    float* __restrict__ Cout,
                                                    int M, int N, int K){
  __shared__ unsigned short As[128 * 32];
  __shared__ unsigned short Bs[128 * 32];
  const int tid = threadIdx.x;
  const int lane = tid & 63, wid = tid >> 6;
  const int l15 = lane & 15, g = lane >> 4;
  const int wr = wid >> 1, wc = wid & 1;
  const int m0 = blockIdx.x * 128, n0 = blockIdx.y * 128;
  const int bcol = tid & 127, bhalf = tid >> 7;
  f32x4 acc[4][4];
  #pragma unroll
  for (int m = 0; m < 4; ++m)
    #pragma unroll
    for (int n = 0; n < 4; ++n)
      #pragma unroll
      for (int i = 0; i < 4; ++i) acc[m][n][i] = 0.0f;
  for (int kk = 0; kk < K; kk += 32){
    __syncthreads();
    #pragma unroll
    for (int cc = 0; cc < 2; ++cc){
      int c = tid + cc * 256;
      int row = c >> 2, kc = (c & 3) << 3;
      uint4 d = *(const uint4*)(A + (size_t)(m0 + row) * K + kk + kc);
      *(uint4*)(&As[row * 32 + kc]) = d;
    }
    {
      const float* bp = Bw + (size_t)(kk + bhalf * 16) * N + n0 + bcol;
      float f[16];
      #pragma unroll
      for (int j = 0; j < 16; ++j) f[j] = bp[(size_t)j * N];
      unsigned int pk[8];
      #pragma unroll
      for (int j = 0; j < 8; ++j)
        pk[j] = (unsigned int)f2bf(f[2*j]) | ((unsigned int)f2bf(f[2*j+1]) << 16);
      int sw = (bcol >> 1) & 3;
      int c0 = ((bhalf << 1)     ) ^ sw;
      int c1 = ((bhalf << 1) | 1 ) ^ sw;
      uint4 w0; w0.x = pk[0]; w0.y = pk[1]; w0.z = pk[2]; w0.w = pk[3];
      uint4 w1; w1.x = pk[4]; w1.y = pk[5]; w1.z = pk[6]; w1.w = pk[7];
      *(uint4*)(&Bs[bcol * 32 + c0 * 8]) = w0;
      *(uint4*)(&Bs[bcol * 32 + c1 * 8]) = w1;
    }
    __syncthreads();
    short8 a[4], b[4];
    #pragma unroll
    for (int m = 0; m < 4; ++m)
      a[m] = *(const short8*)(&As[(wr*64 + m*16 + l15) * 32 + g*8]);
    #pragma unroll
    for (int n = 0; n < 4; ++n){
      int col = wc*64 + n*16 + l15;
      b[n] = *(const short8*)(&Bs[col * 32 + (g ^ ((col >> 1) & 3)) * 8]);
    }
    #pragma unroll
    for (int m = 0; m < 4; ++m)
      #pragma unroll
      for (int n = 0; n < 4; ++n)
        acc[m][n] = __builtin_amdgcn_mfma_f32_16x16x32_bf16(a[m], b[n], acc[m][n], 0, 0, 0);
  }
  #pragma unroll
  for (int m = 0; m < 4; ++m)
    #pragma unroll
    for (int n = 0; n < 4; ++n){
      int row0 = m0 + wr*64 + m*16 + g*4;
      int col  = n0 + wc*64 + n*16 + l15;
      #pragma unroll
      for (int i = 0; i < 4; ++i)
        Cout[(size_t)(row0 + i) * N + col] = acc[m][n][i];
    }
}

// ------- flash attention: 8 waves/block, 16 q-rows per wave, KV tile 64, T14 prefetch ---
__global__ __launch_bounds__(512) void attn_kernel(const unsigned short* __restrict__ q,
                                                   const unsigned short* __restrict__ k,
                                                   const unsigned short* __restrict__ vt,
                                                   unsigned short* __restrict__ ctx){
  const int tid = threadIdx.x;
  const int lane = tid & 63, w = tid >> 6;      // w in [0,8)
  const int l15 = lane & 15, g = lane >> 4;
  const int bx = (int)gridDim.x - 1 - (int)blockIdx.x;  // heavy blocks first
  const int q0 = bx * 128 + w * 16;             // this wave's 16 q rows
  const int hh = blockIdx.y;
  const int tb = blockIdx.z * SEQ;

  __shared__ unsigned short Ks[64][72];    // [kv][d]
  __shared__ unsigned short Vs[64][72];    // [d][t]
  __shared__ unsigned short Ps[8][16][72]; // per-wave P round-trip

  short8 qa[2];
  #pragma unroll
  for (int kd = 0; kd < 2; ++kd)
    qa[kd] = *(const short8*)(q + (size_t)(tb + q0 + l15) * HID + hh*HD + kd*32 + g*8);

  float m_run[4], l_run[4];
  f32x4 o_acc[4];
  #pragma unroll
  for (int i = 0; i < 4; ++i){ m_run[i] = -1e30f; l_run[i] = 0.0f; }
  #pragma unroll
  for (int dt = 0; dt < 4; ++dt)
    #pragma unroll
    for (int i = 0; i < 4; ++i) o_acc[dt][i] = 0.0f;

  const int ntile = 2 * bx + 2;
  const int srow = tid >> 3, sc = (tid & 7) * 8;   // 512 threads: one uint4 each
  const unsigned short* kbase = k  + (size_t)(tb + srow) * HID + hh*HD + sc;
  const unsigned short* vbase = vt + (size_t)(hh*HD + srow) * T_TOK + tb + sc;

  uint4 kreg = *(const uint4*)(kbase);     // tile 0 preload
  uint4 vreg = *(const uint4*)(vbase);

  for (int kt = 0; kt < ntile; ++kt){
    const int kv0 = kt * 64;
    __syncthreads();                       // prev tile's compute done (LDS free)
    *(uint4*)(&Ks[srow][sc]) = kreg;
    *(uint4*)(&Vs[srow][sc]) = vreg;
    __syncthreads();                       // tile visible to all waves
    if (kt + 1 < ntile){                   // T14: issue next-tile loads before compute
      kreg = *(const uint4*)(kbase + (size_t)(kv0 + 64) * HID);
      vreg = *(const uint4*)(vbase + kv0 + 64);
    }
    const int dq = q0 + 15 - kv0;
    const int nct = (dq < 0) ? 0 : min(4, (dq >> 4) + 1);
    if (nct <= 0) continue;                 // barrier counts stay uniform

    float pv[4][4];
    #pragma unroll
    for (int ct = 0; ct < 4; ++ct){
      if (ct < nct){
        f32x4 scv;
        #pragma unroll
        for (int i = 0; i < 4; ++i) scv[i] = 0.0f;
        scv = __builtin_amdgcn_mfma_f32_16x16x32_bf16(qa[0],
                *(const short8*)(&Ks[ct*16 + l15][g*8]), scv, 0, 0, 0);
        scv = __builtin_amdgcn_mfma_f32_16x16x32_bf16(qa[1],
                *(const short8*)(&Ks[ct*16 + l15][32 + g*8]), scv, 0, 0, 0);
        #pragma unroll
        for (int i = 0; i < 4; ++i){
          float s = fminf(fmaxf(scv[i], -1000.0f), 1000.0f);
          int row = q0 + g*4 + i;
          int col = kv0 + ct*16 + l15;
          pv[ct][i] = (col > row) ? -1e30f : s;
        }
      } else {
        #pragma unroll
        for (int i = 0; i < 4; ++i) pv[ct][i] = -1e30f;
      }
    }
    #pragma unroll
    for (int i = 0; i < 4; ++i){
      float mx = fmaxf(fmaxf(pv[0][i], pv[1][i]), fmaxf(pv[2][i], pv[3][i]));
      #pragma unroll
      for (int msk = 1; msk < 16; msk <<= 1) mx = fmaxf(mx, __shfl_xor(mx, msk));
      if (!__all(mx <= m_run[i] + 8.0f)){         // T13 defer-max
        float mnew = fmaxf(m_run[i], mx);
        float scale = __expf(m_run[i] - mnew);
        m_run[i] = mnew;
        l_run[i] *= scale;
        #pragma unroll
        for (int dt = 0; dt < 4; ++dt) o_acc[dt][i] *= scale;
      }
      float psum = 0.0f;
      #pragma unroll
      for (int ct = 0; ct < 4; ++ct){
        if (ct < nct){
          float p = __expf(pv[ct][i] - m_run[i]);
          pv[ct][i] = p; psum += p;
        } else pv[ct][i] = 0.0f;
      }
      #pragma unroll
      for (int msk = 1; msk < 16; msk <<= 1) psum += __shfl_xor(psum, msk);
      l_run[i] += psum;
    }
    #pragma unroll
    for (int ct = 0; ct < 4; ++ct)          // write all 4 (zeros beyond nct)
      #pragma unroll
      for (int i = 0; i < 4; ++i)
        Ps[w][g*4 + i][ct*16 + l15] = f2bf(pv[ct][i]);
    const int nks = (nct + 1) >> 1;
    #pragma unroll
    for (int ks = 0; ks < 2; ++ks){
      if (ks < nks){
        short8 ap = *(const short8*)(&Ps[w][l15][ks*32 + g*8]);
        #pragma unroll
        for (int dt = 0; dt < 4; ++dt){
          short8 vb = *(const short8*)(&Vs[dt*16 + l15][ks*32 + g*8]);
          o_acc[dt] = __builtin_amdgcn_mfma_f32_16x16x32_bf16(ap, vb, o_acc[dt], 0, 0, 0);
        }
      }
    }
  }
  #pragma unroll
  for (int i = 0; i < 4; ++i) l_run[i] = 1.0f / l_run[i];   // one rcp per row
  #pragma unroll
  for (int dt = 0; dt < 4; ++dt)
    #pragma unroll
    for (int i = 0; i < 4; ++i){
      float o = o_acc[dt][i] * l_run[i];
      ctx[(size_t)(tb + q0 + g*4 + i) * HID + hh*HD + dt*16 + l15] = f2bf(o);
    }
}

extern "C" void kernel_launch(void* const* d_in, const int* in_sizes, int n_in,
                              void* d_out, int out_size, void* d_ws, size_t ws_size,
                              hipStream_t stream){
  const int*   ids    = (const int*)d_in[0];
  const float* embedW = (const float*)d_in[1];
  const float* Wq = (const float*)d_in[2];
  const float* Wk = (const float*)d_in[3];
  const float* Wv = (const float*)d_in[4];
  const float* Wo = (const float*)d_in[5];
  const float* Wg = (const float*)d_in[6];
  const float* Wu = (const float*)d_in[7];
  const float* Wd = (const float*)d_in[8];
  const float* n1 = (const float*)d_in[9];
  const float* n2 = (const float*)d_in[10];
  const float* nf = (const float*)d_in[11];
  const float* Wh = (const float*)d_in[12];
  float* out = (float*)d_out;

  // d_out scratch (dead until head GEMM, which reads only ws-resident xn/WhT)
  char* scb = (char*)d_out;
  unsigned short* qb  = (unsigned short*)(scb + 0);
  unsigned short* kb  = (unsigned short*)(scb + 8388608);
  unsigned short* vtb = (unsigned short*)(scb + 16777216);   // V^T [HID][T]
  unsigned short* ctx = (unsigned short*)(scb + 25165824);
  unsigned short* gb  = (unsigned short*)(scb + 33554432);
  float* cosT = (float*)(scb + 100663296);
  float* sinT = (float*)(scb + 100925440);
  float* h_fallback   = (float*)(scb + 104857600);
  unsigned short* WtQ = (unsigned short*)(scb + 134217728);  // 16 MB (Q,K,V,O contiguous)
  unsigned short* WtK = (unsigned short*)(scb + 150994944);
  unsigned short* WtV = (unsigned short*)(scb + 167772160);
  unsigned short* WtO = (unsigned short*)(scb + 184549376);
  unsigned short* WtG = (unsigned short*)(scb + 201326592);  // 64 MB
  unsigned short* WtU = (unsigned short*)(scb + 268435456);  // 64 MB
  unsigned short* WtD = (unsigned short*)(scb + 335544320);  // 64 MB -> ends 384 MB

  unsigned short* xn = (unsigned short*)d_ws;                // 8 MB
  float* h = (ws_size >= 25165824u) ? (float*)((char*)d_ws + 8388608) : h_fallback;
  unsigned short* WhT = (ws_size >= 90701824u)
                      ? (unsigned short*)((char*)d_ws + 25165824) : nullptr;

  // weight converts: QKVO in one launch; G+U in one launch; D; head linear
  convert_w_qkvo<<<dim3(16, 16, 32), 256, 0, stream>>>(Wq, Wk, Wv, Wo, WtQ);
  convert_w_gu<<<dim3(64, 16, 16), 256, 0, stream>>>(Wg, Wu, WtG, WtU);
  convert_w_swz<<<dim3(16, 64, 8), 256, 0, stream>>>(Wd, WtD, INTER, HID);
  if (WhT)
    convert_w_lin<<<dim3(500, 16, 1), 256, 0, stream>>>(Wh, WhT, HID, VOCAB);

  embed_kernel<<<4096, 256, 0, stream>>>(ids, embedW, h);
  rope_tab_kernel<<<256, 256, 0, stream>>>(cosT, sinT);

  for (int l = 0; l < NLAYER; ++l){
    rmsnorm_kernel<<<4096, 256, 0, stream>>>(h, n1 + l*HID, xn, nullptr);
    gemm_qkv<<<dim3(32, 24), 256, 0, stream>>>(xn, WtQ + (size_t)l*HID*HID,
                                               WtK + (size_t)l*HID*HID,
                                               WtV + (size_t)l*HID*HID, qb, kb, vtb,
                                               cosT, sinT);
    attn_kernel<<<dim3(16, 16, 2), 512, 0, stream>>>(qb, kb, vtb, ctx);
    gemm_od<<<dim3(64, 8), 256, 0, stream>>>(ctx, WtO + (size_t)l*HID*HID,
                                             h, h, HID, HID);
    rmsnorm_kernel<<<4096, 256, 0, stream>>>(h, n2 + l*HID, xn, nullptr);
    gemm_gusilu<<<dim3(32, 32), 256, 0, stream>>>(xn, WtG + (size_t)l*HID*INTER,
                                                  WtU + (size_t)l*HID*INTER, gb);
    gemm_od<<<dim3(64, 8), 256, 0, stream>>>(gb, WtD + (size_t)l*HID*INTER,
                                             h, h, INTER, HID);
  }

  rmsnorm_kernel<<<4096, 256, 0, stream>>>(h, nf, xn, out + 131072000);
  if (WhT)
    gemm_head8p<<<dim3(16, 125), 512, 0, stream>>>(xn, WhT, out);
  else
    gemm_f32b<<<dim3(32, 250), 256, 0, stream>>>(xn, Wh, out, T_TOK, VOCAB, HID);
}